// Round 7
// baseline (2190.293 us; speedup 1.0000x reference)
//
#include <hip/hip_runtime.h>
#include <hip/hip_fp16.h>
#include <cstdint>
#include <cstddef>

// Problem constants (setup_inputs: B=8,S=2048,D=768,E=8,I=3072,H=1536,top_k=2)
#define TK 16384   // tokens
#define DD 768
#define EE 8
#define II 3072
#define HH 1536

typedef _Float16 half8 __attribute__((ext_vector_type(8)));
typedef float floatx4 __attribute__((ext_vector_type(4)));

typedef const __attribute__((address_space(1))) uint32_t* gptr_t;
typedef __attribute__((address_space(3))) uint32_t* lptr_t;

#define GLOAD_LDS16(gp, lp) __builtin_amdgcn_global_load_lds( \
    (gptr_t)(const void*)(gp), (lptr_t)(void*)(lp), 16, 0, 0)

// Bijective XCD chunk swizzle: all gridDim.x N-tiles of one (e,m) land on one
// XCD contiguously (A-panel L2 reuse). Bijective because gridDim.z==8 makes
// total % (8*G) == 0 with G = gridDim.x.  [T1/m204]
// REV flips global order: consumer reads producer's FRESHEST output first,
// catching it in L3 before this kernel's own traffic evicts it.
__device__ inline void xcd_swizzle(int& e, int& m, int& n, bool rev) {
  int gx = gridDim.x, gy = gridDim.y;
  int f = (blockIdx.z * gy + blockIdx.y) * gx + blockIdx.x;
  if (rev) f = gx * gy * 8 - 1 - f;
  int xcd = f & 7, idx = f >> 3;
  int chunk = idx / gx, pos = idx - chunk * gx;
  int logical = chunk * (8 * gx) + xcd * gx + pos;
  int mn = gy * gx;
  e = logical / mn;
  int rem = logical - e * mn;
  m = rem / gx;
  n = rem - m * gx;
}

// ------- fp32 [E][K][N] -> fp16 [E][N][K] transpose-convert (64x64 tiles) -------
__global__ __launch_bounds__(256)
void cvtT_kernel(const float* __restrict__ in, __half* __restrict__ out,
                 int K, int N) {
  __shared__ float tile[64][65];
  int e = blockIdx.z;
  const float* inp = in + (size_t)e * K * N + (size_t)(blockIdx.y * 64) * N + blockIdx.x * 64;
  __half* outp = out + (size_t)e * K * N + (size_t)(blockIdx.x * 64) * K + blockIdx.y * 64;
  int s = threadIdx.x;
  int tx = s & 15, r0 = s >> 4;           // tx: float4 col group, r0: row 0..15
#pragma unroll
  for (int i = 0; i < 4; ++i) {
    int k = r0 + i * 16;
    float4 v = *(const float4*)&inp[(size_t)k * N + tx * 4];
    tile[k][tx * 4 + 0] = v.x;
    tile[k][tx * 4 + 1] = v.y;
    tile[k][tx * 4 + 2] = v.z;
    tile[k][tx * 4 + 3] = v.w;
  }
  __syncthreads();
  int kp = s & 31;                         // k-pair 0..31
#pragma unroll
  for (int i = 0; i < 8; ++i) {
    int n = (s >> 5) + i * 8;
    __half2 h = __floats2half2_rn(tile[2 * kp][n], tile[2 * kp + 1][n]);
    *(__half2*)&outp[(size_t)n * K + kp * 2] = h;
  }
}

// ------- router: fp32 logits, top-2, softmax; also emits xh (fp16 copy of x) -------
__global__ __launch_bounds__(256)
void router_kernel(const float* __restrict__ x, const float* __restrict__ Wr,
                   const float* __restrict__ br, int* __restrict__ counts,
                   int* __restrict__ sel, float* __restrict__ wTok,
                   __half* __restrict__ xh) {
  __shared__ float wr_s[EE * DD];  // transposed [e][d], 24KB
  for (int i = threadIdx.x; i < EE * DD; i += 256) {
    int d = i >> 3, e = i & 7;
    wr_s[e * DD + d] = Wr[i];
  }
  __syncthreads();
  int wid = threadIdx.x >> 6, lane = threadIdx.x & 63;
  int t = blockIdx.x * 4 + wid;
  const float* xt = x + (size_t)t * DD;
  float acc[EE];
#pragma unroll
  for (int e = 0; e < EE; ++e) acc[e] = 0.f;
  for (int d = lane; d < DD; d += 64) {
    float xv = xt[d];
#pragma unroll
    for (int e = 0; e < EE; ++e) acc[e] += xv * wr_s[e * DD + d];
  }
#pragma unroll
  for (int off = 32; off > 0; off >>= 1)
#pragma unroll
    for (int e = 0; e < EE; ++e) acc[e] += __shfl_xor(acc[e], off);
  if (lane == 0) {
    float v[EE];
#pragma unroll
    for (int e = 0; e < EE; ++e) v[e] = acc[e] + br[e];
    int i0 = 0;
#pragma unroll
    for (int e = 1; e < EE; ++e) if (v[e] > v[i0]) i0 = e;
    int i1 = (i0 == 0) ? 1 : 0;
#pragma unroll
    for (int e = 0; e < EE; ++e) if (e != i0 && v[e] > v[i1] && e != i1) { if (v[e] > v[i1]) i1 = e; }
    float e1 = __expf(v[i1] - v[i0]);
    float s = 1.f / (1.f + e1);
    sel[2 * t] = i0; sel[2 * t + 1] = i1;
    wTok[2 * t] = s; wTok[2 * t + 1] = e1 * s;
    atomicAdd(&counts[i0], 1);
    atomicAdd(&counts[i1], 1);
  }
  // fused x -> fp16 conversion for this wave's token row
  const float4* xr = (const float4*)xt;
  uint2* xo = (uint2*)(xh + (size_t)t * DD);
#pragma unroll
  for (int j = 0; j < 3; ++j) {
    float4 v = xr[lane + j * 64];
    __half2 a = __floats2half2_rn(v.x, v.y);
    __half2 b = __floats2half2_rn(v.z, v.w);
    uint2 p;
    p.x = *(const unsigned int*)&a;
    p.y = *(const unsigned int*)&b;
    xo[lane + j * 64] = p;
  }
}

// ---------------- offsets (prefix over 8) ----------------
__global__ void offsets_kernel(const int* __restrict__ counts, int* __restrict__ offsets,
                               int* __restrict__ cursors) {
  if (threadIdx.x == 0) {
    int o = 0;
    for (int e = 0; e < EE; ++e) { offsets[e] = o; cursors[e] = o; o += counts[e]; }
  }
}

// ---------------- scatter token->slot ----------------
__global__ void scatter_kernel(const int* __restrict__ sel, int* __restrict__ cursors,
                               int* __restrict__ idxList, int* __restrict__ posTok) {
  int t = blockIdx.x * 256 + threadIdx.x;
  if (t < TK) {
#pragma unroll
    for (int k = 0; k < 2; ++k) {
      int e = sel[2 * t + k];
      int p = atomicAdd(&cursors[e], 1);
      idxList[p] = t;
      posTok[2 * t + k] = p;
    }
  }
}

// ---------------- FFN GEMM (8-phase 256x256, deep-A prefetch) ----------------
// 8 waves (2Mx4N), BK=64, dbuf, quarter-granular staging, counted vmcnt(6),
// setprio, XOR-swizzled LDS.  R7 reorder: ALL A-fragment ds_reads happen in
// phase a (af[8][2] live), so ALL FOUR A-quarter stages of tile t+2 issue at
// phase b -> A issue-to-wait distance = 6 phases (~960cy) >= HBM-miss ~900cy.
// B stages keep 3-phase distance (L3-warm).  Hazard ledger:
//  - STAGE_A(CUR,q,t+2)@b: all af reads of CUR drained by a's lgkmcnt(0);
//    stage issues after a's trailing barrier.
//  - STAGE_B(CUR,q0/q1,t+2)@c: bf0@a, bf1@b drained by b's lgkmcnt(0).
//  - STAGE_B(NXT,q2/q3,t+1)@a: NXT's B reads happened at (t-1).a/b.
//  - end-of-tile vmcnt(6): newest-6 outstanding = A(t+2)x4 + B01(t+2)x2;
//    everything of tile t+1 is older -> landed.  Prologue issues
//    A(0),B(0),A(1),B01(1) = steady-state entry; tails drop to vmcnt(0).
template<int KD, int ND, bool GATHER, bool GELU, bool REV>
__global__ __launch_bounds__(512, 1)
void ffn_gemm8(const __half* __restrict__ A, const __half* __restrict__ Wt,
               const float* __restrict__ Bias, __half* __restrict__ Out,
               const int* __restrict__ counts, const int* __restrict__ offsets,
               const int* __restrict__ idxList) {
  constexpr int NT = KD / 64;
  int e, mblk, nblk;
  xcd_swizzle(e, mblk, nblk, REV);
  const int cnt = counts[e];
  const int m0 = mblk * 256;
  if (cnt == 0 || m0 >= cnt) return;
  const int off = offsets[e];
  const int n0 = nblk * 256;
  const __half* We = Wt + (size_t)e * KD * ND;
  const float* be = Bias + (size_t)e * ND;

  __shared__ __align__(16) __half As[2][256 * 64];
  __shared__ __align__(16) __half Bs[2][256 * 64];

  const int tid = threadIdx.x;
  const int srow = tid >> 3;                 // 0..63 row within quarter
  const int swz = ((tid & 7) ^ (srow & 7)) << 3;

  const __half* aptr[4];
  const __half* bptr[4];
#pragma unroll
  for (int q = 0; q < 4; ++q) {
    int gr = m0 + q * 64 + srow;
    if (gr > cnt - 1) gr = cnt - 1;          // clamp tail (writes guarded)
    size_t arow = GATHER ? (size_t)idxList[off + gr] : (size_t)(off + gr);
    aptr[q] = A + arow * KD + swz;
    bptr[q] = We + (size_t)(n0 + q * 64 + srow) * KD + swz;
  }

#define STAGE_A(BUF, Q, TS) GLOAD_LDS16(aptr[Q] + (TS) * 64, &As[BUF][(Q) * 4096 + tid * 8])
#define STAGE_B(BUF, Q, TS) GLOAD_LDS16(bptr[Q] + (TS) * 64, &Bs[BUF][(Q) * 4096 + tid * 8])

  const int lane = tid & 63, wv = tid >> 6;
  const int wr = wv >> 2, wc = wv & 3;       // 2 x 4 wave grid
  const int lrow = lane & 15, lg = lane >> 4;
  const int rowa = wr * 128 + lrow;
  const int rowb = wc * 64 + lrow;
  int aoff[2], boff[2];
#pragma unroll
  for (int kk = 0; kk < 2; ++kk) {
    aoff[kk] = rowa * 64 + (((kk * 4 + lg) ^ (rowa & 7)) << 3);
    boff[kk] = rowb * 64 + (((kk * 4 + lg) ^ (rowb & 7)) << 3);
  }

  floatx4 acc[8][4];
#pragma unroll
  for (int mi = 0; mi < 8; ++mi)
#pragma unroll
    for (int ni = 0; ni < 4; ++ni) acc[mi][ni] = (floatx4){0.f, 0.f, 0.f, 0.f};

  // ---- prologue: tile0 fully; tile1's A + B-q0,q1 (B-q2,q3 staged at t0.a) ----
#pragma unroll
  for (int q = 0; q < 4; ++q) STAGE_A(0, q, 0);
#pragma unroll
  for (int q = 0; q < 4; ++q) STAGE_B(0, q, 0);
#pragma unroll
  for (int q = 0; q < 4; ++q) STAGE_A(1, q, 1);
  STAGE_B(1, 0, 1);
  STAGE_B(1, 1, 1);
  asm volatile("s_waitcnt vmcnt(6)" ::: "memory");   // tile0's 8 quarters landed
  __builtin_amdgcn_s_barrier();

#define BAR() __builtin_amdgcn_s_barrier()
#define WLG() do { asm volatile("s_waitcnt lgkmcnt(0)" ::: "memory"); \
                   __builtin_amdgcn_sched_barrier(0); } while (0)
#define P1() __builtin_amdgcn_s_setprio(1)
#define P0() __builtin_amdgcn_s_setprio(0)
#define MMQ(AO, BF, MB, NB) \
  _Pragma("unroll") for (int kk = 0; kk < 2; ++kk) \
  _Pragma("unroll") for (int mi = 0; mi < 4; ++mi) \
  _Pragma("unroll") for (int ni = 0; ni < 2; ++ni) \
    acc[(MB) + mi][(NB) + ni] = __builtin_amdgcn_mfma_f32_16x16x32_f16( \
        af[(AO) + mi][kk], BF[ni][kk], acc[(MB) + mi][(NB) + ni], 0, 0, 0);

#define PHASES(CUR, NXT, TT) { \
  const __half* Ac = &As[CUR][0]; \
  const __half* Bc = &Bs[CUR][0]; \
  half8 af[8][2], bf0[2][2], bf1[2][2]; \
  /* phase a: ALL A frags (16 reads) + bf0; stage B-q2,q3(t+1) */ \
  _Pragma("unroll") for (int mi = 0; mi < 8; ++mi) \
  _Pragma("unroll") for (int kk = 0; kk < 2; ++kk) \
    af[mi][kk] = *(const half8*)&Ac[aoff[kk] + mi * 1024]; \
  _Pragma("unroll") for (int ni = 0; ni < 2; ++ni) \
  _Pragma("unroll") for (int kk = 0; kk < 2; ++kk) \
    bf0[ni][kk] = *(const half8*)&Bc[boff[kk] + ni * 1024]; \
  if ((TT) + 1 < NT) { STAGE_B(NXT, 2, (TT) + 1); STAGE_B(NXT, 3, (TT) + 1); } \
  BAR(); WLG(); P1(); MMQ(0, bf0, 0, 0); P0(); BAR(); \
  /* phase b: bf1; stage ALL A(t+2) into CUR (A region read-free after a) */ \
  _Pragma("unroll") for (int ni = 0; ni < 2; ++ni) \
  _Pragma("unroll") for (int kk = 0; kk < 2; ++kk) \
    bf1[ni][kk] = *(const half8*)&Bc[boff[kk] + (ni + 2) * 1024]; \
  if ((TT) + 2 < NT) { STAGE_A(CUR, 0, (TT) + 2); STAGE_A(CUR, 1, (TT) + 2); \
                       STAGE_A(CUR, 2, (TT) + 2); STAGE_A(CUR, 3, (TT) + 2); } \
  BAR(); WLG(); P1(); MMQ(0, bf1, 0, 2); P0(); BAR(); \
  /* phase c: stage B-q0,q1(t+2) (B region read-free after b) */ \
  if ((TT) + 2 < NT) { STAGE_B(CUR, 0, (TT) + 2); STAGE_B(CUR, 1, (TT) + 2); } \
  BAR(); P1(); MMQ(4, bf0, 4, 0); P0(); BAR(); \
  /* phase d: pure MFMA; counted wait for next tile */ \
  P1(); MMQ(4, bf1, 4, 2); P0(); \
  if ((TT) + 2 < NT) { asm volatile("s_waitcnt vmcnt(6)" ::: "memory"); } \
  else              { asm volatile("s_waitcnt vmcnt(0)" ::: "memory"); } \
  BAR(); }

  for (int t = 0; t < NT; t += 2) {
    PHASES(0, 1, t)
    PHASES(1, 0, t + 1)
  }

  // ---- epilogue: bias + optional erf-GELU, guarded rows ----
  const int crow = m0 + wr * 128 + lg * 4;
  const int ccol = n0 + wc * 64 + lrow;
  float bv[4];
#pragma unroll
  for (int ni = 0; ni < 4; ++ni) bv[ni] = be[ccol + ni * 16];
#pragma unroll
  for (int mi = 0; mi < 8; ++mi) {
#pragma unroll
    for (int j = 0; j < 4; ++j) {
      int r = crow + mi * 16 + j;
      if (r < cnt) {
#pragma unroll
        for (int ni = 0; ni < 4; ++ni) {
          float v = acc[mi][ni][j] + bv[ni];
          if (GELU) v = 0.5f * v * (1.f + erff(v * 0.70710678118654752f));
          Out[(size_t)(off + r) * ND + ccol + ni * 16] = __float2half(v);
        }
      }
    }
  }
#undef STAGE_A
#undef STAGE_B
#undef BAR
#undef WLG
#undef P1
#undef P0
#undef MMQ
#undef PHASES
}

// ---------------- combine: out[t] = w0*yc[p0] + w1*yc[p1] ----------------
__global__ void combine_kernel(const __half* __restrict__ yc, const float* __restrict__ wTok,
                               const int* __restrict__ posTok, float* __restrict__ out) {
  int t = blockIdx.x;
  int d = threadIdx.x * 4;
  if (d >= DD) return;
  float w0 = wTok[2 * t], w1 = wTok[2 * t + 1];
  const __half2* a = (const __half2*)(yc + (size_t)posTok[2 * t] * DD + d);
  const __half2* b = (const __half2*)(yc + (size_t)posTok[2 * t + 1] * DD + d);
  float2 a0 = __half22float2(a[0]), a1 = __half22float2(a[1]);
  float2 b0 = __half22float2(b[0]), b1 = __half22float2(b[1]);
  float4 r;
  r.x = w0 * a0.x + w1 * b0.x;
  r.y = w0 * a0.y + w1 * b0.y;
  r.z = w0 * a1.x + w1 * b1.x;
  r.w = w0 * a1.y + w1 * b1.y;
  *(float4*)(out + (size_t)t * DD + d) = r;
}

extern "C" void kernel_launch(void* const* d_in, const int* in_sizes, int n_in,
                              void* d_out, int out_size, void* d_ws, size_t ws_size,
                              hipStream_t stream) {
  const float* x  = (const float*)d_in[0];
  const float* Wr = (const float*)d_in[1];
  const float* br = (const float*)d_in[2];
  const float* W1 = (const float*)d_in[3];
  const float* b1 = (const float*)d_in[4];
  const float* W2 = (const float*)d_in[5];
  const float* b2 = (const float*)d_in[6];
  const float* W3 = (const float*)d_in[7];
  const float* b3 = (const float*)d_in[8];
  float* out = (float*)d_out;

  char* ws = (char*)d_ws;
  size_t o = 0;
  auto alloc = [&](size_t bytes) {
    char* p = ws + o;
    o += (bytes + 255) & ~(size_t)255;
    return p;
  };
  __half* xh   = (__half*)alloc((size_t)TK * DD * 2);
  __half* w1t  = (__half*)alloc((size_t)EE * DD * II * 2);
  __half* w2t  = (__half*)alloc((size_t)EE * II * HH * 2);
  __half* w3t  = (__half*)alloc((size_t)EE * HH * DD * 2);
  __half* h1   = (__half*)alloc((size_t)2 * TK * II * 2);
  __half* h2   = (__half*)alloc((size_t)2 * TK * HH * 2);
  __half* yc   = (__half*)alloc((size_t)2 * TK * DD * 2);
  int*   idxL  = (int*)alloc(2 * TK * 4);
  int*   sel   = (int*)alloc(2 * TK * 4);
  float* wTok  = (float*)alloc(2 * TK * 4);
  int*   posT  = (int*)alloc(2 * TK * 4);
  int*   counts  = (int*)alloc(256);
  int*   offsets = (int*)alloc(256);
  int*   cursors = (int*)alloc(256);
  if (o > ws_size) return;  // workspace too small -> loud absmax failure

  hipMemsetAsync(counts, 0, 256, stream);

  cvtT_kernel<<<dim3(II / 64, DD / 64, EE), 256, 0, stream>>>(W1, w1t, DD, II);
  cvtT_kernel<<<dim3(HH / 64, II / 64, EE), 256, 0, stream>>>(W2, w2t, II, HH);
  cvtT_kernel<<<dim3(DD / 64, HH / 64, EE), 256, 0, stream>>>(W3, w3t, HH, DD);
  router_kernel<<<TK / 4, 256, 0, stream>>>(x, Wr, br, counts, sel, wTok, xh);
  offsets_kernel<<<1, 64, 0, stream>>>(counts, offsets, cursors);
  scatter_kernel<<<TK / 256, 256, 0, stream>>>(sel, cursors, idxL, posT);

  // stage-2 REV=true: read h1 freshest-first (L3); it then writes h2 descending,
  // so stage-3's default ascending order reads h2 freshest-first too.
  ffn_gemm8<DD, II, true,  true,  false><<<dim3(II / 256, 64, EE), 512, 0, stream>>>(
      xh, w1t, b1, h1, counts, offsets, idxL);
  ffn_gemm8<II, HH, false, true,  true ><<<dim3(HH / 256, 64, EE), 512, 0, stream>>>(
      h1, w2t, b2, h2, counts, offsets, idxL);
  ffn_gemm8<HH, DD, false, false, false><<<dim3(DD / 256, 64, EE), 512, 0, stream>>>(
      h2, w3t, b3, yc, counts, offsets, idxL);

  combine_kernel<<<TK, 192, 0, stream>>>(yc, wTok, posT, out);
}

// Round 8
// 1917.722 us; speedup vs baseline: 1.1421x; 1.1421x over previous
//
#include <hip/hip_runtime.h>
#include <hip/hip_fp16.h>
#include <cstdint>
#include <cstddef>

// Problem constants (setup_inputs: B=8,S=2048,D=768,E=8,I=3072,H=1536,top_k=2)
#define TK 16384   // tokens
#define DD 768
#define EE 8
#define II 3072
#define HH 1536

typedef _Float16 half8 __attribute__((ext_vector_type(8)));
typedef float floatx4 __attribute__((ext_vector_type(4)));

typedef const __attribute__((address_space(1))) uint32_t* gptr_t;
typedef __attribute__((address_space(3))) uint32_t* lptr_t;

#define GLOAD_LDS16(gp, lp) __builtin_amdgcn_global_load_lds( \
    (gptr_t)(const void*)(gp), (lptr_t)(void*)(lp), 16, 0, 0)

// Bijective XCD chunk swizzle: all gridDim.x N-tiles of one (e,m) land on one
// XCD contiguously (A-panel L2 reuse). Bijective because gridDim.z==8 makes
// total % (8*G) == 0 with G = gridDim.x.  [T1/m204]
__device__ inline void xcd_swizzle(int& e, int& m, int& n) {
  int gx = gridDim.x, gy = gridDim.y;
  int f = (blockIdx.z * gy + blockIdx.y) * gx + blockIdx.x;
  int xcd = f & 7, idx = f >> 3;
  int chunk = idx / gx, pos = idx - chunk * gx;
  int logical = chunk * (8 * gx) + xcd * gx + pos;
  int mn = gy * gx;
  e = logical / mn;
  int rem = logical - e * mn;
  m = rem / gx;
  n = rem - m * gx;
}

// ------- fp32 [E][K][N] -> fp16 [E][N][K] transpose-convert (64x64 tiles) -------
__global__ __launch_bounds__(256)
void cvtT_kernel(const float* __restrict__ in, __half* __restrict__ out,
                 int K, int N) {
  __shared__ float tile[64][65];
  int e = blockIdx.z;
  const float* inp = in + (size_t)e * K * N + (size_t)(blockIdx.y * 64) * N + blockIdx.x * 64;
  __half* outp = out + (size_t)e * K * N + (size_t)(blockIdx.x * 64) * K + blockIdx.y * 64;
  int s = threadIdx.x;
  int tx = s & 15, r0 = s >> 4;           // tx: float4 col group, r0: row 0..15
#pragma unroll
  for (int i = 0; i < 4; ++i) {
    int k = r0 + i * 16;
    float4 v = *(const float4*)&inp[(size_t)k * N + tx * 4];
    tile[k][tx * 4 + 0] = v.x;
    tile[k][tx * 4 + 1] = v.y;
    tile[k][tx * 4 + 2] = v.z;
    tile[k][tx * 4 + 3] = v.w;
  }
  __syncthreads();
  int kp = s & 31;                         // k-pair 0..31
#pragma unroll
  for (int i = 0; i < 8; ++i) {
    int n = (s >> 5) + i * 8;
    __half2 h = __floats2half2_rn(tile[2 * kp][n], tile[2 * kp + 1][n]);
    *(__half2*)&outp[(size_t)n * K + kp * 2] = h;
  }
}

// ------- router: fp32 logits, top-2, softmax; also emits xh (fp16 copy of x) -------
__global__ __launch_bounds__(256)
void router_kernel(const float* __restrict__ x, const float* __restrict__ Wr,
                   const float* __restrict__ br, int* __restrict__ counts,
                   int* __restrict__ sel, float* __restrict__ wTok,
                   __half* __restrict__ xh) {
  __shared__ float wr_s[EE * DD];  // transposed [e][d], 24KB
  for (int i = threadIdx.x; i < EE * DD; i += 256) {
    int d = i >> 3, e = i & 7;
    wr_s[e * DD + d] = Wr[i];
  }
  __syncthreads();
  int wid = threadIdx.x >> 6, lane = threadIdx.x & 63;
  int t = blockIdx.x * 4 + wid;
  const float* xt = x + (size_t)t * DD;
  float acc[EE];
#pragma unroll
  for (int e = 0; e < EE; ++e) acc[e] = 0.f;
  for (int d = lane; d < DD; d += 64) {
    float xv = xt[d];
#pragma unroll
    for (int e = 0; e < EE; ++e) acc[e] += xv * wr_s[e * DD + d];
  }
#pragma unroll
  for (int off = 32; off > 0; off >>= 1)
#pragma unroll
    for (int e = 0; e < EE; ++e) acc[e] += __shfl_xor(acc[e], off);
  if (lane == 0) {
    float v[EE];
#pragma unroll
    for (int e = 0; e < EE; ++e) v[e] = acc[e] + br[e];
    int i0 = 0;
#pragma unroll
    for (int e = 1; e < EE; ++e) if (v[e] > v[i0]) i0 = e;
    int i1 = (i0 == 0) ? 1 : 0;
#pragma unroll
    for (int e = 0; e < EE; ++e) if (e != i0 && v[e] > v[i1] && e != i1) { if (v[e] > v[i1]) i1 = e; }
    float e1 = __expf(v[i1] - v[i0]);
    float s = 1.f / (1.f + e1);
    sel[2 * t] = i0; sel[2 * t + 1] = i1;
    wTok[2 * t] = s; wTok[2 * t + 1] = e1 * s;
    atomicAdd(&counts[i0], 1);
    atomicAdd(&counts[i1], 1);
  }
  // fused x -> fp16 conversion for this wave's token row
  const float4* xr = (const float4*)xt;
  uint2* xo = (uint2*)(xh + (size_t)t * DD);
#pragma unroll
  for (int j = 0; j < 3; ++j) {
    float4 v = xr[lane + j * 64];
    __half2 a = __floats2half2_rn(v.x, v.y);
    __half2 b = __floats2half2_rn(v.z, v.w);
    uint2 p;
    p.x = *(const unsigned int*)&a;
    p.y = *(const unsigned int*)&b;
    xo[lane + j * 64] = p;
  }
}

// ---------------- offsets (prefix over 8) ----------------
__global__ void offsets_kernel(const int* __restrict__ counts, int* __restrict__ offsets,
                               int* __restrict__ cursors) {
  if (threadIdx.x == 0) {
    int o = 0;
    for (int e = 0; e < EE; ++e) { offsets[e] = o; cursors[e] = o; o += counts[e]; }
  }
}

// ---------------- scatter token->slot ----------------
__global__ void scatter_kernel(const int* __restrict__ sel, int* __restrict__ cursors,
                               int* __restrict__ idxList, int* __restrict__ posTok) {
  int t = blockIdx.x * 256 + threadIdx.x;
  if (t < TK) {
#pragma unroll
    for (int k = 0; k < 2; ++k) {
      int e = sel[2 * t + k];
      int p = atomicAdd(&cursors[e], 1);
      idxList[p] = t;
      posTok[2 * t + k] = p;
    }
  }
}

// ---------------- FFN GEMM (8-phase 256x256, A triple-buffered in LDS) ------
// 8 waves (2Mx4N), BK=64, quarter-granular staging, counted vmcnt(6), setprio,
// XOR-swizzled LDS.  As[3] (96KB) + Bs[2] (64KB) = 160KB LDS.
// Schedule (tile t):  A reads As[t%3], B reads Bs[t%2].
//  phase a: ds af[0..3]+bf0 | stage B(t+1)q2,q3 -> Bs[(t+1)%2];
//           stage A(t+2)q0..q3 -> As[(t+2)%3]   (that buf last read tile t-1)
//  phase b: ds bf1           | -
//  phase c: ds af[4..7]      | stage B(t+2)q0,q1 -> Bs[t%2]  (q0q1 read@a only)
//  phase d: -                | vmcnt(6): newest-6 = B(t+2)q0q1 + A(t+2)x4,
//           forces B(t+1)q2q3 and older => tile t+1 fully landed.
// A issue->wait distance = 7 phases (~1100cy) > HBM-miss ~900cy; register live
// set identical to R6 (af[4][2] at a time) -- no spills (R7 lesson).
template<int KD, int ND, bool GATHER, bool GELU>
__global__ __launch_bounds__(512, 1)
void ffn_gemm8(const __half* __restrict__ A, const __half* __restrict__ Wt,
               const float* __restrict__ Bias, __half* __restrict__ Out,
               const int* __restrict__ counts, const int* __restrict__ offsets,
               const int* __restrict__ idxList) {
  constexpr int NT = KD / 64;                // 12 / 48 / 24 — all divisible by 6
  int e, mblk, nblk;
  xcd_swizzle(e, mblk, nblk);
  const int cnt = counts[e];
  const int m0 = mblk * 256;
  if (cnt == 0 || m0 >= cnt) return;
  const int off = offsets[e];
  const int n0 = nblk * 256;
  const __half* We = Wt + (size_t)e * KD * ND;
  const float* be = Bias + (size_t)e * ND;

  __shared__ __align__(16) __half As[3][256 * 64];   // 96 KB
  __shared__ __align__(16) __half Bs[2][256 * 64];   // 64 KB

  const int tid = threadIdx.x;
  const int srow = tid >> 3;                 // 0..63 row within quarter
  const int swz = ((tid & 7) ^ (srow & 7)) << 3;

  const __half* aptr[4];
  const __half* bptr[4];
#pragma unroll
  for (int q = 0; q < 4; ++q) {
    int gr = m0 + q * 64 + srow;
    if (gr > cnt - 1) gr = cnt - 1;          // clamp tail (writes guarded)
    size_t arow = GATHER ? (size_t)idxList[off + gr] : (size_t)(off + gr);
    aptr[q] = A + arow * KD + swz;
    bptr[q] = We + (size_t)(n0 + q * 64 + srow) * KD + swz;
  }

#define STAGE_A(BUF, Q, TS) GLOAD_LDS16(aptr[Q] + (TS) * 64, &As[BUF][(Q) * 4096 + tid * 8])
#define STAGE_B(BUF, Q, TS) GLOAD_LDS16(bptr[Q] + (TS) * 64, &Bs[BUF][(Q) * 4096 + tid * 8])

  const int lane = tid & 63, wv = tid >> 6;
  const int wr = wv >> 2, wc = wv & 3;       // 2 x 4 wave grid
  const int lrow = lane & 15, lg = lane >> 4;
  const int rowa = wr * 128 + lrow;
  const int rowb = wc * 64 + lrow;
  int aoff[2], boff[2];
#pragma unroll
  for (int kk = 0; kk < 2; ++kk) {
    aoff[kk] = rowa * 64 + (((kk * 4 + lg) ^ (rowa & 7)) << 3);
    boff[kk] = rowb * 64 + (((kk * 4 + lg) ^ (rowb & 7)) << 3);
  }

  floatx4 acc[8][4];
#pragma unroll
  for (int mi = 0; mi < 8; ++mi)
#pragma unroll
    for (int ni = 0; ni < 4; ++ni) acc[mi][ni] = (floatx4){0.f, 0.f, 0.f, 0.f};

  // ---- prologue: B(0), A(0), B(1)q0q1, A(1); A(2) staged in-loop at t0.a ----
#pragma unroll
  for (int q = 0; q < 4; ++q) STAGE_B(0, q, 0);
#pragma unroll
  for (int q = 0; q < 4; ++q) STAGE_A(0, q, 0);
  STAGE_B(1, 0, 1);
  STAGE_B(1, 1, 1);
#pragma unroll
  for (int q = 0; q < 4; ++q) STAGE_A(1, q, 1);
  // newest 6 = A(1)x4 + B(1)q0q1 -> forces A(0),B(0) landed
  asm volatile("s_waitcnt vmcnt(6)" ::: "memory");
  __builtin_amdgcn_s_barrier();

#define BAR() __builtin_amdgcn_s_barrier()
#define WLG() do { asm volatile("s_waitcnt lgkmcnt(0)" ::: "memory"); \
                   __builtin_amdgcn_sched_barrier(0); } while (0)
#define P1() __builtin_amdgcn_s_setprio(1)
#define P0() __builtin_amdgcn_s_setprio(0)
#define MMQ(AF, BF, MB, NB) \
  _Pragma("unroll") for (int kk = 0; kk < 2; ++kk) \
  _Pragma("unroll") for (int mi = 0; mi < 4; ++mi) \
  _Pragma("unroll") for (int ni = 0; ni < 2; ++ni) \
    acc[(MB) + mi][(NB) + ni] = __builtin_amdgcn_mfma_f32_16x16x32_f16( \
        AF[mi][kk], BF[ni][kk], acc[(MB) + mi][(NB) + ni], 0, 0, 0);

#define PHASES(AC, AN2, BC, BN, TT) { \
  const __half* Ac = &As[AC][0]; \
  const __half* Bc = &Bs[BC][0]; \
  half8 af[4][2], ag[4][2], bf0[2][2], bf1[2][2]; \
  /* phase a: af[0..3] + bf0; stage B(t+1)q2q3 then A(t+2)x4 */ \
  _Pragma("unroll") for (int mi = 0; mi < 4; ++mi) \
  _Pragma("unroll") for (int kk = 0; kk < 2; ++kk) \
    af[mi][kk] = *(const half8*)&Ac[aoff[kk] + mi * 1024]; \
  _Pragma("unroll") for (int ni = 0; ni < 2; ++ni) \
  _Pragma("unroll") for (int kk = 0; kk < 2; ++kk) \
    bf0[ni][kk] = *(const half8*)&Bc[boff[kk] + ni * 1024]; \
  if ((TT) + 1 < NT) { STAGE_B(BN, 2, (TT) + 1); STAGE_B(BN, 3, (TT) + 1); } \
  if ((TT) + 2 < NT) { STAGE_A(AN2, 0, (TT) + 2); STAGE_A(AN2, 1, (TT) + 2); \
                       STAGE_A(AN2, 2, (TT) + 2); STAGE_A(AN2, 3, (TT) + 2); } \
  BAR(); WLG(); P1(); MMQ(af, bf0, 0, 0); P0(); BAR(); \
  /* phase b: bf1 */ \
  _Pragma("unroll") for (int ni = 0; ni < 2; ++ni) \
  _Pragma("unroll") for (int kk = 0; kk < 2; ++kk) \
    bf1[ni][kk] = *(const half8*)&Bc[boff[kk] + (ni + 2) * 1024]; \
  BAR(); WLG(); P1(); MMQ(af, bf1, 0, 2); P0(); BAR(); \
  /* phase c: af[4..7]; stage B(t+2)q0q1 into BC (its q0q1 reads drained @a) */ \
  _Pragma("unroll") for (int mi = 0; mi < 4; ++mi) \
  _Pragma("unroll") for (int kk = 0; kk < 2; ++kk) \
    ag[mi][kk] = *(const half8*)&Ac[aoff[kk] + (mi + 4) * 1024]; \
  if ((TT) + 2 < NT) { STAGE_B(BC, 0, (TT) + 2); STAGE_B(BC, 1, (TT) + 2); } \
  BAR(); WLG(); P1(); MMQ(ag, bf0, 4, 0); P0(); BAR(); \
  /* phase d: pure MFMA; counted wait -> tile t+1 landed */ \
  P1(); MMQ(ag, bf1, 4, 2); P0(); \
  if ((TT) + 2 < NT) { asm volatile("s_waitcnt vmcnt(6)" ::: "memory"); } \
  else              { asm volatile("s_waitcnt vmcnt(0)" ::: "memory"); } \
  BAR(); }

  for (int t = 0; t < NT; t += 6) {
    PHASES(0, 2, 0, 1, t)
    PHASES(1, 0, 1, 0, t + 1)
    PHASES(2, 1, 0, 1, t + 2)
    PHASES(0, 2, 1, 0, t + 3)
    PHASES(1, 0, 0, 1, t + 4)
    PHASES(2, 1, 1, 0, t + 5)
  }

  // ---- epilogue: bias + optional erf-GELU, guarded rows ----
  const int crow = m0 + wr * 128 + lg * 4;
  const int ccol = n0 + wc * 64 + lrow;
  float bv[4];
#pragma unroll
  for (int ni = 0; ni < 4; ++ni) bv[ni] = be[ccol + ni * 16];
#pragma unroll
  for (int mi = 0; mi < 8; ++mi) {
#pragma unroll
    for (int j = 0; j < 4; ++j) {
      int r = crow + mi * 16 + j;
      if (r < cnt) {
#pragma unroll
        for (int ni = 0; ni < 4; ++ni) {
          float v = acc[mi][ni][j] + bv[ni];
          if (GELU) v = 0.5f * v * (1.f + erff(v * 0.70710678118654752f));
          Out[(size_t)(off + r) * ND + ccol + ni * 16] = __float2half(v);
        }
      }
    }
  }
#undef STAGE_A
#undef STAGE_B
#undef BAR
#undef WLG
#undef P1
#undef P0
#undef MMQ
#undef PHASES
}

// ---------------- combine: out[t] = w0*yc[p0] + w1*yc[p1] ----------------
__global__ void combine_kernel(const __half* __restrict__ yc, const float* __restrict__ wTok,
                               const int* __restrict__ posTok, float* __restrict__ out) {
  int t = blockIdx.x;
  int d = threadIdx.x * 4;
  if (d >= DD) return;
  float w0 = wTok[2 * t], w1 = wTok[2 * t + 1];
  const __half2* a = (const __half2*)(yc + (size_t)posTok[2 * t] * DD + d);
  const __half2* b = (const __half2*)(yc + (size_t)posTok[2 * t + 1] * DD + d);
  float2 a0 = __half22float2(a[0]), a1 = __half22float2(a[1]);
  float2 b0 = __half22float2(b[0]), b1 = __half22float2(b[1]);
  float4 r;
  r.x = w0 * a0.x + w1 * b0.x;
  r.y = w0 * a0.y + w1 * b0.y;
  r.z = w0 * a1.x + w1 * b1.x;
  r.w = w0 * a1.y + w1 * b1.y;
  *(float4*)(out + (size_t)t * DD + d) = r;
}

extern "C" void kernel_launch(void* const* d_in, const int* in_sizes, int n_in,
                              void* d_out, int out_size, void* d_ws, size_t ws_size,
                              hipStream_t stream) {
  const float* x  = (const float*)d_in[0];
  const float* Wr = (const float*)d_in[1];
  const float* br = (const float*)d_in[2];
  const float* W1 = (const float*)d_in[3];
  const float* b1 = (const float*)d_in[4];
  const float* W2 = (const float*)d_in[5];
  const float* b2 = (const float*)d_in[6];
  const float* W3 = (const float*)d_in[7];
  const float* b3 = (const float*)d_in[8];
  float* out = (float*)d_out;

  char* ws = (char*)d_ws;
  size_t o = 0;
  auto alloc = [&](size_t bytes) {
    char* p = ws + o;
    o += (bytes + 255) & ~(size_t)255;
    return p;
  };
  __half* xh   = (__half*)alloc((size_t)TK * DD * 2);
  __half* w1t  = (__half*)alloc((size_t)EE * DD * II * 2);
  __half* w2t  = (__half*)alloc((size_t)EE * II * HH * 2);
  __half* w3t  = (__half*)alloc((size_t)EE * HH * DD * 2);
  __half* h1   = (__half*)alloc((size_t)2 * TK * II * 2);
  __half* h2   = (__half*)alloc((size_t)2 * TK * HH * 2);
  __half* yc   = (__half*)alloc((size_t)2 * TK * DD * 2);
  int*   idxL  = (int*)alloc(2 * TK * 4);
  int*   sel   = (int*)alloc(2 * TK * 4);
  float* wTok  = (float*)alloc(2 * TK * 4);
  int*   posT  = (int*)alloc(2 * TK * 4);
  int*   counts  = (int*)alloc(256);
  int*   offsets = (int*)alloc(256);
  int*   cursors = (int*)alloc(256);
  if (o > ws_size) return;  // workspace too small -> loud absmax failure

  hipMemsetAsync(counts, 0, 256, stream);

  cvtT_kernel<<<dim3(II / 64, DD / 64, EE), 256, 0, stream>>>(W1, w1t, DD, II);
  cvtT_kernel<<<dim3(HH / 64, II / 64, EE), 256, 0, stream>>>(W2, w2t, II, HH);
  cvtT_kernel<<<dim3(DD / 64, HH / 64, EE), 256, 0, stream>>>(W3, w3t, HH, DD);
  router_kernel<<<TK / 4, 256, 0, stream>>>(x, Wr, br, counts, sel, wTok, xh);
  offsets_kernel<<<1, 64, 0, stream>>>(counts, offsets, cursors);
  scatter_kernel<<<TK / 256, 256, 0, stream>>>(sel, cursors, idxL, posT);

  ffn_gemm8<DD, II, true,  true ><<<dim3(II / 256, 64, EE), 512, 0, stream>>>(
      xh, w1t, b1, h1, counts, offsets, idxL);
  ffn_gemm8<II, HH, false, true ><<<dim3(HH / 256, 64, EE), 512, 0, stream>>>(
      h1, w2t, b2, h2, counts, offsets, idxL);
  ffn_gemm8<HH, DD, false, false><<<dim3(DD / 256, 64, EE), 512, 0, stream>>>(
      h2, w3t, b3, yc, counts, offsets, idxL);

  combine_kernel<<<TK, 192, 0, stream>>>(yc, wTok, posT, out);
}

// Round 9
// 1914.589 us; speedup vs baseline: 1.1440x; 1.0016x over previous
//
#include <hip/hip_runtime.h>
#include <hip/hip_fp16.h>
#include <cstdint>
#include <cstddef>

// Problem constants (setup_inputs: B=8,S=2048,D=768,E=8,I=3072,H=1536,top_k=2)
#define TK 16384   // tokens
#define DD 768
#define EE 8
#define II 3072
#define HH 1536

typedef _Float16 half8 __attribute__((ext_vector_type(8)));
typedef float floatx4 __attribute__((ext_vector_type(4)));

typedef const __attribute__((address_space(1))) uint32_t* gptr_t;
typedef __attribute__((address_space(3))) uint32_t* lptr_t;

#define GLOAD_LDS16(gp, lp) __builtin_amdgcn_global_load_lds( \
    (gptr_t)(const void*)(gp), (lptr_t)(void*)(lp), 16, 0, 0)

// Bijective XCD chunk swizzle: all gridDim.x N-tiles of one (e,m) land on one
// XCD contiguously (A-panel L2 reuse). Bijective because gridDim.z==8 makes
// total % (8*G) == 0 with G = gridDim.x.  [T1/m204]
__device__ inline void xcd_swizzle(int& e, int& m, int& n) {
  int gx = gridDim.x, gy = gridDim.y;
  int f = (blockIdx.z * gy + blockIdx.y) * gx + blockIdx.x;
  int xcd = f & 7, idx = f >> 3;
  int chunk = idx / gx, pos = idx - chunk * gx;
  int logical = chunk * (8 * gx) + xcd * gx + pos;
  int mn = gy * gx;
  e = logical / mn;
  int rem = logical - e * mn;
  m = rem / gx;
  n = rem - m * gx;
}

// ------- fp32 [E][K][N] -> fp16 [E][N][K] transpose-convert (64x64 tiles) -------
__global__ __launch_bounds__(256)
void cvtT_kernel(const float* __restrict__ in, __half* __restrict__ out,
                 int K, int N) {
  __shared__ float tile[64][65];
  int e = blockIdx.z;
  const float* inp = in + (size_t)e * K * N + (size_t)(blockIdx.y * 64) * N + blockIdx.x * 64;
  __half* outp = out + (size_t)e * K * N + (size_t)(blockIdx.x * 64) * K + blockIdx.y * 64;
  int s = threadIdx.x;
  int tx = s & 15, r0 = s >> 4;           // tx: float4 col group, r0: row 0..15
#pragma unroll
  for (int i = 0; i < 4; ++i) {
    int k = r0 + i * 16;
    float4 v = *(const float4*)&inp[(size_t)k * N + tx * 4];
    tile[k][tx * 4 + 0] = v.x;
    tile[k][tx * 4 + 1] = v.y;
    tile[k][tx * 4 + 2] = v.z;
    tile[k][tx * 4 + 3] = v.w;
  }
  __syncthreads();
  int kp = s & 31;                         // k-pair 0..31
#pragma unroll
  for (int i = 0; i < 8; ++i) {
    int n = (s >> 5) + i * 8;
    __half2 h = __floats2half2_rn(tile[2 * kp][n], tile[2 * kp + 1][n]);
    *(__half2*)&outp[(size_t)n * K + kp * 2] = h;
  }
}

// ------- router: fp32 logits, top-2, softmax; also emits xh (fp16 copy of x) -------
__global__ __launch_bounds__(256)
void router_kernel(const float* __restrict__ x, const float* __restrict__ Wr,
                   const float* __restrict__ br, int* __restrict__ counts,
                   int* __restrict__ sel, float* __restrict__ wTok,
                   __half* __restrict__ xh) {
  __shared__ float wr_s[EE * DD];  // transposed [e][d], 24KB
  for (int i = threadIdx.x; i < EE * DD; i += 256) {
    int d = i >> 3, e = i & 7;
    wr_s[e * DD + d] = Wr[i];
  }
  __syncthreads();
  int wid = threadIdx.x >> 6, lane = threadIdx.x & 63;
  int t = blockIdx.x * 4 + wid;
  const float* xt = x + (size_t)t * DD;
  float acc[EE];
#pragma unroll
  for (int e = 0; e < EE; ++e) acc[e] = 0.f;
  for (int d = lane; d < DD; d += 64) {
    float xv = xt[d];
#pragma unroll
    for (int e = 0; e < EE; ++e) acc[e] += xv * wr_s[e * DD + d];
  }
#pragma unroll
  for (int off = 32; off > 0; off >>= 1)
#pragma unroll
    for (int e = 0; e < EE; ++e) acc[e] += __shfl_xor(acc[e], off);
  if (lane == 0) {
    float v[EE];
#pragma unroll
    for (int e = 0; e < EE; ++e) v[e] = acc[e] + br[e];
    int i0 = 0;
#pragma unroll
    for (int e = 1; e < EE; ++e) if (v[e] > v[i0]) i0 = e;
    int i1 = (i0 == 0) ? 1 : 0;
#pragma unroll
    for (int e = 0; e < EE; ++e) if (e != i0 && v[e] > v[i1] && e != i1) { if (v[e] > v[i1]) i1 = e; }
    float e1 = __expf(v[i1] - v[i0]);
    float s = 1.f / (1.f + e1);
    sel[2 * t] = i0; sel[2 * t + 1] = i1;
    wTok[2 * t] = s; wTok[2 * t + 1] = e1 * s;
    atomicAdd(&counts[i0], 1);
    atomicAdd(&counts[i1], 1);
  }
  // fused x -> fp16 conversion for this wave's token row
  const float4* xr = (const float4*)xt;
  uint2* xo = (uint2*)(xh + (size_t)t * DD);
#pragma unroll
  for (int j = 0; j < 3; ++j) {
    float4 v = xr[lane + j * 64];
    __half2 a = __floats2half2_rn(v.x, v.y);
    __half2 b = __floats2half2_rn(v.z, v.w);
    uint2 p;
    p.x = *(const unsigned int*)&a;
    p.y = *(const unsigned int*)&b;
    xo[lane + j * 64] = p;
  }
}

// ---------------- offsets (prefix over 8) ----------------
__global__ void offsets_kernel(const int* __restrict__ counts, int* __restrict__ offsets,
                               int* __restrict__ cursors) {
  if (threadIdx.x == 0) {
    int o = 0;
    for (int e = 0; e < EE; ++e) { offsets[e] = o; cursors[e] = o; o += counts[e]; }
  }
}

// ---------------- scatter token->slot ----------------
__global__ void scatter_kernel(const int* __restrict__ sel, int* __restrict__ cursors,
                               int* __restrict__ idxList, int* __restrict__ posTok) {
  int t = blockIdx.x * 256 + threadIdx.x;
  if (t < TK) {
#pragma unroll
    for (int k = 0; k < 2; ++k) {
      int e = sel[2 * t + k];
      int p = atomicAdd(&cursors[e], 1);
      idxList[p] = t;
      posTok[2 * t + k] = p;
    }
  }
}

// ---------------- FFN GEMM (8-phase 256x256, A triple-buffered in LDS) ------
// 8 waves (2Mx4N), BK=64, quarter-granular staging, counted vmcnt(6), setprio,
// XOR-swizzled LDS.  As[3] (96KB) + Bs[2] (64KB) = 160KB LDS.
// Schedule (tile t):  A reads As[t%3], B reads Bs[t%2].
//  phase a: ds af[0..3]+bf0 | stage B(t+1)q2,q3 -> Bs[(t+1)%2];
//           stage A(t+2)q0..q3 -> As[(t+2)%3]   (that buf last read tile t-1,
//           reads drained by t-1.c's lgkmcnt(0) + barriers)
//  phase b: ds bf1           | -
//  phase c: ds af[4..7] REUSING af (R6 register pattern — R7/R8 lesson:
//           acc(128 AGPR)+VGPR(128) is EXACTLY the 256/wave cap at 8 waves;
//           one extra named fragment array spills to scratch) |
//           stage B(t+2)q0,q1 -> Bs[t%2]  (q0q1 reads drained @a)
//  phase d: -                | vmcnt(6): newest-6 = B(t+2)q0q1 + A(t+2)x4,
//           forces B(t+1)q2q3 and older => tile t+1 fully landed.
// A issue->wait distance = 7 phases (~1100cy) > HBM-miss ~900cy.
template<int KD, int ND, bool GATHER, bool GELU>
__global__ __launch_bounds__(512, 1)
void ffn_gemm8(const __half* __restrict__ A, const __half* __restrict__ Wt,
               const float* __restrict__ Bias, __half* __restrict__ Out,
               const int* __restrict__ counts, const int* __restrict__ offsets,
               const int* __restrict__ idxList) {
  constexpr int NT = KD / 64;                // 12 / 48 / 24 — all divisible by 6
  int e, mblk, nblk;
  xcd_swizzle(e, mblk, nblk);
  const int cnt = counts[e];
  const int m0 = mblk * 256;
  if (cnt == 0 || m0 >= cnt) return;
  const int off = offsets[e];
  const int n0 = nblk * 256;
  const __half* We = Wt + (size_t)e * KD * ND;
  const float* be = Bias + (size_t)e * ND;

  __shared__ __align__(16) __half As[3][256 * 64];   // 96 KB
  __shared__ __align__(16) __half Bs[2][256 * 64];   // 64 KB

  const int tid = threadIdx.x;
  const int srow = tid >> 3;                 // 0..63 row within quarter
  const int swz = ((tid & 7) ^ (srow & 7)) << 3;

  const __half* aptr[4];
  const __half* bptr[4];
#pragma unroll
  for (int q = 0; q < 4; ++q) {
    int gr = m0 + q * 64 + srow;
    if (gr > cnt - 1) gr = cnt - 1;          // clamp tail (writes guarded)
    size_t arow = GATHER ? (size_t)idxList[off + gr] : (size_t)(off + gr);
    aptr[q] = A + arow * KD + swz;
    bptr[q] = We + (size_t)(n0 + q * 64 + srow) * KD + swz;
  }

#define STAGE_A(BUF, Q, TS) GLOAD_LDS16(aptr[Q] + (TS) * 64, &As[BUF][(Q) * 4096 + tid * 8])
#define STAGE_B(BUF, Q, TS) GLOAD_LDS16(bptr[Q] + (TS) * 64, &Bs[BUF][(Q) * 4096 + tid * 8])

  const int lane = tid & 63, wv = tid >> 6;
  const int wr = wv >> 2, wc = wv & 3;       // 2 x 4 wave grid
  const int lrow = lane & 15, lg = lane >> 4;
  const int rowa = wr * 128 + lrow;
  const int rowb = wc * 64 + lrow;
  int aoff[2], boff[2];
#pragma unroll
  for (int kk = 0; kk < 2; ++kk) {
    aoff[kk] = rowa * 64 + (((kk * 4 + lg) ^ (rowa & 7)) << 3);
    boff[kk] = rowb * 64 + (((kk * 4 + lg) ^ (rowb & 7)) << 3);
  }

  floatx4 acc[8][4];
#pragma unroll
  for (int mi = 0; mi < 8; ++mi)
#pragma unroll
    for (int ni = 0; ni < 4; ++ni) acc[mi][ni] = (floatx4){0.f, 0.f, 0.f, 0.f};

  // ---- prologue: B(0), A(0), B(1)q0q1, A(1); A(2) staged in-loop at t0.a ----
#pragma unroll
  for (int q = 0; q < 4; ++q) STAGE_B(0, q, 0);
#pragma unroll
  for (int q = 0; q < 4; ++q) STAGE_A(0, q, 0);
  STAGE_B(1, 0, 1);
  STAGE_B(1, 1, 1);
#pragma unroll
  for (int q = 0; q < 4; ++q) STAGE_A(1, q, 1);
  // newest 6 = A(1)x4 + B(1)q0q1 -> forces A(0),B(0) landed
  asm volatile("s_waitcnt vmcnt(6)" ::: "memory");
  __builtin_amdgcn_s_barrier();

#define BAR() __builtin_amdgcn_s_barrier()
#define WLG() do { asm volatile("s_waitcnt lgkmcnt(0)" ::: "memory"); \
                   __builtin_amdgcn_sched_barrier(0); } while (0)
#define P1() __builtin_amdgcn_s_setprio(1)
#define P0() __builtin_amdgcn_s_setprio(0)
#define MMQ(AF, BF, MB, NB) \
  _Pragma("unroll") for (int kk = 0; kk < 2; ++kk) \
  _Pragma("unroll") for (int mi = 0; mi < 4; ++mi) \
  _Pragma("unroll") for (int ni = 0; ni < 2; ++ni) \
    acc[(MB) + mi][(NB) + ni] = __builtin_amdgcn_mfma_f32_16x16x32_f16( \
        AF[mi][kk], BF[ni][kk], acc[(MB) + mi][(NB) + ni], 0, 0, 0);

#define PHASES(AC, AN2, BC, BN, TT) { \
  const __half* Ac = &As[AC][0]; \
  const __half* Bc = &Bs[BC][0]; \
  half8 af[4][2], bf0[2][2], bf1[2][2]; \
  /* phase a: af[0..3] + bf0; stage B(t+1)q2q3 then A(t+2)x4 */ \
  _Pragma("unroll") for (int mi = 0; mi < 4; ++mi) \
  _Pragma("unroll") for (int kk = 0; kk < 2; ++kk) \
    af[mi][kk] = *(const half8*)&Ac[aoff[kk] + mi * 1024]; \
  _Pragma("unroll") for (int ni = 0; ni < 2; ++ni) \
  _Pragma("unroll") for (int kk = 0; kk < 2; ++kk) \
    bf0[ni][kk] = *(const half8*)&Bc[boff[kk] + ni * 1024]; \
  if ((TT) + 1 < NT) { STAGE_B(BN, 2, (TT) + 1); STAGE_B(BN, 3, (TT) + 1); } \
  if ((TT) + 2 < NT) { STAGE_A(AN2, 0, (TT) + 2); STAGE_A(AN2, 1, (TT) + 2); \
                       STAGE_A(AN2, 2, (TT) + 2); STAGE_A(AN2, 3, (TT) + 2); } \
  BAR(); WLG(); P1(); MMQ(af, bf0, 0, 0); P0(); BAR(); \
  /* phase b: bf1 */ \
  _Pragma("unroll") for (int ni = 0; ni < 2; ++ni) \
  _Pragma("unroll") for (int kk = 0; kk < 2; ++kk) \
    bf1[ni][kk] = *(const half8*)&Bc[boff[kk] + (ni + 2) * 1024]; \
  BAR(); WLG(); P1(); MMQ(af, bf1, 0, 2); P0(); BAR(); \
  /* phase c: af <- frags 4..7 (REUSE); stage B(t+2)q0q1 into BC */ \
  _Pragma("unroll") for (int mi = 0; mi < 4; ++mi) \
  _Pragma("unroll") for (int kk = 0; kk < 2; ++kk) \
    af[mi][kk] = *(const half8*)&Ac[aoff[kk] + (mi + 4) * 1024]; \
  if ((TT) + 2 < NT) { STAGE_B(BC, 0, (TT) + 2); STAGE_B(BC, 1, (TT) + 2); } \
  BAR(); WLG(); P1(); MMQ(af, bf0, 4, 0); P0(); BAR(); \
  /* phase d: pure MFMA; counted wait -> tile t+1 landed */ \
  P1(); MMQ(af, bf1, 4, 2); P0(); \
  if ((TT) + 2 < NT) { asm volatile("s_waitcnt vmcnt(6)" ::: "memory"); } \
  else              { asm volatile("s_waitcnt vmcnt(0)" ::: "memory"); } \
  BAR(); }

  for (int t = 0; t < NT; t += 6) {
    PHASES(0, 2, 0, 1, t)
    PHASES(1, 0, 1, 0, t + 1)
    PHASES(2, 1, 0, 1, t + 2)
    PHASES(0, 2, 1, 0, t + 3)
    PHASES(1, 0, 0, 1, t + 4)
    PHASES(2, 1, 1, 0, t + 5)
  }

  // ---- epilogue: bias + optional erf-GELU, guarded rows ----
  const int crow = m0 + wr * 128 + lg * 4;
  const int ccol = n0 + wc * 64 + lrow;
  float bv[4];
#pragma unroll
  for (int ni = 0; ni < 4; ++ni) bv[ni] = be[ccol + ni * 16];
#pragma unroll
  for (int mi = 0; mi < 8; ++mi) {
#pragma unroll
    for (int j = 0; j < 4; ++j) {
      int r = crow + mi * 16 + j;
      if (r < cnt) {
#pragma unroll
        for (int ni = 0; ni < 4; ++ni) {
          float v = acc[mi][ni][j] + bv[ni];
          if (GELU) v = 0.5f * v * (1.f + erff(v * 0.70710678118654752f));
          Out[(size_t)(off + r) * ND + ccol + ni * 16] = __float2half(v);
        }
      }
    }
  }
#undef STAGE_A
#undef STAGE_B
#undef BAR
#undef WLG
#undef P1
#undef P0
#undef MMQ
#undef PHASES
}

// ---------------- combine: out[t] = w0*yc[p0] + w1*yc[p1] ----------------
__global__ void combine_kernel(const __half* __restrict__ yc, const float* __restrict__ wTok,
                               const int* __restrict__ posTok, float* __restrict__ out) {
  int t = blockIdx.x;
  int d = threadIdx.x * 4;
  if (d >= DD) return;
  float w0 = wTok[2 * t], w1 = wTok[2 * t + 1];
  const __half2* a = (const __half2*)(yc + (size_t)posTok[2 * t] * DD + d);
  const __half2* b = (const __half2*)(yc + (size_t)posTok[2 * t + 1] * DD + d);
  float2 a0 = __half22float2(a[0]), a1 = __half22float2(a[1]);
  float2 b0 = __half22float2(b[0]), b1 = __half22float2(b[1]);
  float4 r;
  r.x = w0 * a0.x + w1 * b0.x;
  r.y = w0 * a0.y + w1 * b0.y;
  r.z = w0 * a1.x + w1 * b1.x;
  r.w = w0 * a1.y + w1 * b1.y;
  *(float4*)(out + (size_t)t * DD + d) = r;
}

extern "C" void kernel_launch(void* const* d_in, const int* in_sizes, int n_in,
                              void* d_out, int out_size, void* d_ws, size_t ws_size,
                              hipStream_t stream) {
  const float* x  = (const float*)d_in[0];
  const float* Wr = (const float*)d_in[1];
  const float* br = (const float*)d_in[2];
  const float* W1 = (const float*)d_in[3];
  const float* b1 = (const float*)d_in[4];
  const float* W2 = (const float*)d_in[5];
  const float* b2 = (const float*)d_in[6];
  const float* W3 = (const float*)d_in[7];
  const float* b3 = (const float*)d_in[8];
  float* out = (float*)d_out;

  char* ws = (char*)d_ws;
  size_t o = 0;
  auto alloc = [&](size_t bytes) {
    char* p = ws + o;
    o += (bytes + 255) & ~(size_t)255;
    return p;
  };
  __half* xh   = (__half*)alloc((size_t)TK * DD * 2);
  __half* w1t  = (__half*)alloc((size_t)EE * DD * II * 2);
  __half* w2t  = (__half*)alloc((size_t)EE * II * HH * 2);
  __half* w3t  = (__half*)alloc((size_t)EE * HH * DD * 2);
  __half* h1   = (__half*)alloc((size_t)2 * TK * II * 2);
  __half* h2   = (__half*)alloc((size_t)2 * TK * HH * 2);
  __half* yc   = (__half*)alloc((size_t)2 * TK * DD * 2);
  int*   idxL  = (int*)alloc(2 * TK * 4);
  int*   sel   = (int*)alloc(2 * TK * 4);
  float* wTok  = (float*)alloc(2 * TK * 4);
  int*   posT  = (int*)alloc(2 * TK * 4);
  int*   counts  = (int*)alloc(256);
  int*   offsets = (int*)alloc(256);
  int*   cursors = (int*)alloc(256);
  if (o > ws_size) return;  // workspace too small -> loud absmax failure

  hipMemsetAsync(counts, 0, 256, stream);

  cvtT_kernel<<<dim3(II / 64, DD / 64, EE), 256, 0, stream>>>(W1, w1t, DD, II);
  cvtT_kernel<<<dim3(HH / 64, II / 64, EE), 256, 0, stream>>>(W2, w2t, II, HH);
  cvtT_kernel<<<dim3(DD / 64, HH / 64, EE), 256, 0, stream>>>(W3, w3t, HH, DD);
  router_kernel<<<TK / 4, 256, 0, stream>>>(x, Wr, br, counts, sel, wTok, xh);
  offsets_kernel<<<1, 64, 0, stream>>>(counts, offsets, cursors);
  scatter_kernel<<<TK / 256, 256, 0, stream>>>(sel, cursors, idxL, posT);

  ffn_gemm8<DD, II, true,  true ><<<dim3(II / 256, 64, EE), 512, 0, stream>>>(
      xh, w1t, b1, h1, counts, offsets, idxL);
  ffn_gemm8<II, HH, false, true ><<<dim3(HH / 256, 64, EE), 512, 0, stream>>>(
      h1, w2t, b2, h2, counts, offsets, idxL);
  ffn_gemm8<HH, DD, false, false><<<dim3(DD / 256, 64, EE), 512, 0, stream>>>(
      h2, w3t, b3, yc, counts, offsets, idxL);

  combine_kernel<<<TK, 192, 0, stream>>>(yc, wTok, posT, out);
}

// Round 11
// 1499.733 us; speedup vs baseline: 1.4605x; 1.2766x over previous
//
#include <hip/hip_runtime.h>
#include <hip/hip_fp16.h>
#include <cstdint>
#include <cstddef>

// Problem constants (setup_inputs: B=8,S=2048,D=768,E=8,I=3072,H=1536,top_k=2)
#define TK 16384   // tokens
#define DD 768
#define EE 8
#define II 3072
#define HH 1536

typedef _Float16 half8 __attribute__((ext_vector_type(8)));
typedef float floatx4 __attribute__((ext_vector_type(4)));

typedef const __attribute__((address_space(1))) uint32_t* gptr_t;
typedef __attribute__((address_space(3))) uint32_t* lptr_t;

#define GLOAD_LDS16(gp, lp) __builtin_amdgcn_global_load_lds( \
    (gptr_t)(const void*)(gp), (lptr_t)(void*)(lp), 16, 0, 0)

// Bijective XCD chunk swizzle (T1/m204). REV flips global order so the
// consumer reads the producer's FRESHEST output first (L3-resident tail).
__device__ __forceinline__ void xcd_swizzle(int& e, int& m, int& n, bool rev) {
  int gx = gridDim.x, gy = gridDim.y;
  int f = (blockIdx.z * gy + blockIdx.y) * gx + blockIdx.x;
  if (rev) f = gx * gy * 8 - 1 - f;
  int xcd = f & 7, idx = f >> 3;
  int chunk = idx / gx, pos = idx - chunk * gx;
  int logical = chunk * (8 * gx) + xcd * gx + pos;
  int mn = gy * gx;
  e = logical / mn;
  int rem = logical - e * mn;
  m = rem / gx;
  n = rem - m * gx;
}

// ------- fp32 [E][K][N] -> fp16 [E][N][K] transpose-convert (64x64 tiles) -------
__global__ __launch_bounds__(256)
void cvtT_kernel(const float* __restrict__ in, __half* __restrict__ out,
                 int K, int N) {
  __shared__ float tile[64][65];
  int e = blockIdx.z;
  const float* inp = in + (size_t)e * K * N + (size_t)(blockIdx.y * 64) * N + blockIdx.x * 64;
  __half* outp = out + (size_t)e * K * N + (size_t)(blockIdx.x * 64) * K + blockIdx.y * 64;
  int s = threadIdx.x;
  int tx = s & 15, r0 = s >> 4;           // tx: float4 col group, r0: row 0..15
#pragma unroll
  for (int i = 0; i < 4; ++i) {
    int k = r0 + i * 16;
    float4 v = *(const float4*)&inp[(size_t)k * N + tx * 4];
    tile[k][tx * 4 + 0] = v.x;
    tile[k][tx * 4 + 1] = v.y;
    tile[k][tx * 4 + 2] = v.z;
    tile[k][tx * 4 + 3] = v.w;
  }
  __syncthreads();
  int kp = s & 31;                         // k-pair 0..31
#pragma unroll
  for (int i = 0; i < 8; ++i) {
    int n = (s >> 5) + i * 8;
    __half2 h = __floats2half2_rn(tile[2 * kp][n], tile[2 * kp + 1][n]);
    *(__half2*)&outp[(size_t)n * K + kp * 2] = h;
  }
}

// ------- router: fp32 logits, top-2, softmax; also emits xh (fp16 copy of x) -------
__global__ __launch_bounds__(256)
void router_kernel(const float* __restrict__ x, const float* __restrict__ Wr,
                   const float* __restrict__ br, int* __restrict__ counts,
                   int* __restrict__ sel, float* __restrict__ wTok,
                   __half* __restrict__ xh) {
  __shared__ float wr_s[EE * DD];  // transposed [e][d], 24KB
  for (int i = threadIdx.x; i < EE * DD; i += 256) {
    int d = i >> 3, e = i & 7;
    wr_s[e * DD + d] = Wr[i];
  }
  __syncthreads();
  int wid = threadIdx.x >> 6, lane = threadIdx.x & 63;
  int t = blockIdx.x * 4 + wid;
  const float* xt = x + (size_t)t * DD;
  float acc[EE];
#pragma unroll
  for (int e = 0; e < EE; ++e) acc[e] = 0.f;
  for (int d = lane; d < DD; d += 64) {
    float xv = xt[d];
#pragma unroll
    for (int e = 0; e < EE; ++e) acc[e] += xv * wr_s[e * DD + d];
  }
#pragma unroll
  for (int off = 32; off > 0; off >>= 1)
#pragma unroll
    for (int e = 0; e < EE; ++e) acc[e] += __shfl_xor(acc[e], off);
  if (lane == 0) {
    float v[EE];
#pragma unroll
    for (int e = 0; e < EE; ++e) v[e] = acc[e] + br[e];
    int i0 = 0;
#pragma unroll
    for (int e = 1; e < EE; ++e) if (v[e] > v[i0]) i0 = e;
    int i1 = (i0 == 0) ? 1 : 0;
#pragma unroll
    for (int e = 0; e < EE; ++e) if (e != i0 && v[e] > v[i1] && e != i1) { if (v[e] > v[i1]) i1 = e; }
    float e1 = __expf(v[i1] - v[i0]);
    float s = 1.f / (1.f + e1);
    sel[2 * t] = i0; sel[2 * t + 1] = i1;
    wTok[2 * t] = s; wTok[2 * t + 1] = e1 * s;
    atomicAdd(&counts[i0], 1);
    atomicAdd(&counts[i1], 1);
  }
  // fused x -> fp16 conversion for this wave's token row
  const float4* xr = (const float4*)xt;
  uint2* xo = (uint2*)(xh + (size_t)t * DD);
#pragma unroll
  for (int j = 0; j < 3; ++j) {
    float4 v = xr[lane + j * 64];
    __half2 a = __floats2half2_rn(v.x, v.y);
    __half2 b = __floats2half2_rn(v.z, v.w);
    uint2 p;
    p.x = *(const unsigned int*)&a;
    p.y = *(const unsigned int*)&b;
    xo[lane + j * 64] = p;
  }
}

// ---------------- offsets (prefix over 8) ----------------
__global__ void offsets_kernel(const int* __restrict__ counts, int* __restrict__ offsets,
                               int* __restrict__ cursors) {
  if (threadIdx.x == 0) {
    int o = 0;
    for (int e = 0; e < EE; ++e) { offsets[e] = o; cursors[e] = o; o += counts[e]; }
  }
}

// ---------------- scatter token->slot ----------------
__global__ void scatter_kernel(const int* __restrict__ sel, int* __restrict__ cursors,
                               int* __restrict__ idxList, int* __restrict__ posTok) {
  int t = blockIdx.x * 256 + threadIdx.x;
  if (t < TK) {
#pragma unroll
    for (int k = 0; k < 2; ++k) {
      int e = sel[2 * t + k];
      int p = atomicAdd(&cursors[e], 1);
      idxList[p] = t;
      posTok[2 * t + k] = p;
    }
  }
}

// ---------------- FFN GEMM body (8-phase 256x256 — EXACT R6/1505us schedule) --
// 8 waves (2Mx4N), BK=64, As[2]+Bs[2]=128KB, quarter-granular staging, counted
// vmcnt(6), setprio, XOR-swizzled LDS.
// A-quarter q holds rows q*64..q*64+63.  af[0..3] (phase a) reads rows
// wr*128+0..63 -> quarters {q0 (wr=0), q2 (wr=1)}.  af[4..7] (phase c) reads
// rows wr*128+64..127 -> quarters {q1, q3}.  Hence:
//  phase a: ds af[0..3]+bf0 | stage B(t+1)q2,q3 -> NXT
//  phase b: ds bf1          | stage A(t+2) q0,q2 -> CUR  (read@a, drained)
//  phase c: ds af[4..7]     | stage B(t+2) q0,q1 -> CUR  (read@a/b, drained)
//  phase d: pure MFMA       | stage A(t+2) q1,q3 -> CUR  (read@c, drained)
//           vmcnt(6): newest-6 = A-q1q3(d) + B-q0q1(c) + A-q0q2(b) ->
//           forces B(t+1)q2q3 and older => tile t+1 fully landed.
// R10 RACE LESSON: staging ALL A-quarters at phase b overwrites q1/q3 before
// phase c reads them. The quarter-split is load-bearing; do not "simplify".
template<int KD, int ND, bool GATHER, bool GELU, bool REV>
__device__ __forceinline__
void ffn_body(const __half* __restrict__ A, const __half* __restrict__ Wt,
              const float* __restrict__ Bias, __half* __restrict__ Out,
              const int* __restrict__ counts, const int* __restrict__ offsets,
              const int* __restrict__ idxList) {
  constexpr int NT = KD / 64;                // 12 / 48 / 24 — all even
  int e, mblk, nblk;
  xcd_swizzle(e, mblk, nblk, REV);
  const int cnt = counts[e];
  const int m0 = mblk * 256;
  if (cnt == 0 || m0 >= cnt) return;
  const int off = offsets[e];
  const int n0 = nblk * 256;
  const __half* We = Wt + (size_t)e * KD * ND;
  const float* be = Bias + (size_t)e * ND;

  __shared__ __align__(16) __half As[2][256 * 64];
  __shared__ __align__(16) __half Bs[2][256 * 64];

  const int tid = threadIdx.x;
  const int srow = tid >> 3;                 // 0..63 row within quarter
  const int swz = ((tid & 7) ^ (srow & 7)) << 3;

  const __half* aptr[4];
  const __half* bptr[4];
#pragma unroll
  for (int q = 0; q < 4; ++q) {
    int gr = m0 + q * 64 + srow;
    if (gr > cnt - 1) gr = cnt - 1;          // clamp tail (writes guarded)
    size_t arow = GATHER ? (size_t)idxList[off + gr] : (size_t)(off + gr);
    aptr[q] = A + arow * KD + swz;
    bptr[q] = We + (size_t)(n0 + q * 64 + srow) * KD + swz;
  }

#define STAGE_A(BUF, Q, TS) GLOAD_LDS16(aptr[Q] + (TS) * 64, &As[BUF][(Q) * 4096 + tid * 8])
#define STAGE_B(BUF, Q, TS) GLOAD_LDS16(bptr[Q] + (TS) * 64, &Bs[BUF][(Q) * 4096 + tid * 8])

  const int lane = tid & 63, wv = tid >> 6;
  const int wr = wv >> 2, wc = wv & 3;       // 2 x 4 wave grid
  const int lrow = lane & 15, lg = lane >> 4;
  const int rowa = wr * 128 + lrow;
  const int rowb = wc * 64 + lrow;
  int aoff[2], boff[2];
#pragma unroll
  for (int kk = 0; kk < 2; ++kk) {
    aoff[kk] = rowa * 64 + (((kk * 4 + lg) ^ (rowa & 7)) << 3);
    boff[kk] = rowb * 64 + (((kk * 4 + lg) ^ (rowb & 7)) << 3);
  }

  floatx4 acc[8][4];
#pragma unroll
  for (int mi = 0; mi < 8; ++mi)
#pragma unroll
    for (int ni = 0; ni < 4; ++ni) acc[mi][ni] = (floatx4){0.f, 0.f, 0.f, 0.f};

  // ---- prologue: tile0 fully, tile1 minus B-q2,q3 (staged at t0.a) ----
#pragma unroll
  for (int q = 0; q < 4; ++q) STAGE_A(0, q, 0);
#pragma unroll
  for (int q = 0; q < 4; ++q) STAGE_B(0, q, 0);
#pragma unroll
  for (int q = 0; q < 4; ++q) STAGE_A(1, q, 1);
  STAGE_B(1, 0, 1);
  STAGE_B(1, 1, 1);
  asm volatile("s_waitcnt vmcnt(6)" ::: "memory");   // tile0's 8 quarters landed
  __builtin_amdgcn_s_barrier();

#define BAR() __builtin_amdgcn_s_barrier()
#define WLG() do { asm volatile("s_waitcnt lgkmcnt(0)" ::: "memory"); \
                   __builtin_amdgcn_sched_barrier(0); } while (0)
#define P1() __builtin_amdgcn_s_setprio(1)
#define P0() __builtin_amdgcn_s_setprio(0)
#define MMQ(AF, BF, MB, NB) \
  _Pragma("unroll") for (int kk = 0; kk < 2; ++kk) \
  _Pragma("unroll") for (int mi = 0; mi < 4; ++mi) \
  _Pragma("unroll") for (int ni = 0; ni < 2; ++ni) \
    acc[(MB) + mi][(NB) + ni] = __builtin_amdgcn_mfma_f32_16x16x32_f16( \
        AF[mi][kk], BF[ni][kk], acc[(MB) + mi][(NB) + ni], 0, 0, 0);

#define PHASES(CUR, NXT, TT) { \
  const __half* Ac = &As[CUR][0]; \
  const __half* Bc = &Bs[CUR][0]; \
  half8 af[4][2], bf0[2][2], bf1[2][2]; \
  /* phase a: af[0..3] + bf0; stage B(t+1)q2q3 -> NXT */ \
  _Pragma("unroll") for (int mi = 0; mi < 4; ++mi) \
  _Pragma("unroll") for (int kk = 0; kk < 2; ++kk) \
    af[mi][kk] = *(const half8*)&Ac[aoff[kk] + mi * 1024]; \
  _Pragma("unroll") for (int ni = 0; ni < 2; ++ni) \
  _Pragma("unroll") for (int kk = 0; kk < 2; ++kk) \
    bf0[ni][kk] = *(const half8*)&Bc[boff[kk] + ni * 1024]; \
  if ((TT) + 1 < NT) { STAGE_B(NXT, 2, (TT) + 1); STAGE_B(NXT, 3, (TT) + 1); } \
  BAR(); WLG(); P1(); MMQ(af, bf0, 0, 0); P0(); BAR(); \
  /* phase b: bf1; stage A(t+2) q0,q2 -> CUR (their reads drained @a) */ \
  _Pragma("unroll") for (int ni = 0; ni < 2; ++ni) \
  _Pragma("unroll") for (int kk = 0; kk < 2; ++kk) \
    bf1[ni][kk] = *(const half8*)&Bc[boff[kk] + (ni + 2) * 1024]; \
  if ((TT) + 2 < NT) { STAGE_A(CUR, 0, (TT) + 2); STAGE_A(CUR, 2, (TT) + 2); } \
  BAR(); WLG(); P1(); MMQ(af, bf1, 0, 2); P0(); BAR(); \
  /* phase c: af <- frags 4..7 (q1,q3 rows); stage B(t+2)q0q1 -> CUR */ \
  _Pragma("unroll") for (int mi = 0; mi < 4; ++mi) \
  _Pragma("unroll") for (int kk = 0; kk < 2; ++kk) \
    af[mi][kk] = *(const half8*)&Ac[aoff[kk] + (mi + 4) * 1024]; \
  if ((TT) + 2 < NT) { STAGE_B(CUR, 0, (TT) + 2); STAGE_B(CUR, 1, (TT) + 2); } \
  BAR(); WLG(); P1(); MMQ(af, bf0, 4, 0); P0(); BAR(); \
  /* phase d: stage A(t+2) q1,q3 -> CUR (their reads drained @c); pure MFMA */ \
  if ((TT) + 2 < NT) { STAGE_A(CUR, 1, (TT) + 2); STAGE_A(CUR, 3, (TT) + 2); } \
  BAR(); P1(); MMQ(af, bf1, 4, 2); P0(); \
  if ((TT) + 2 < NT) { asm volatile("s_waitcnt vmcnt(6)" ::: "memory"); } \
  else              { asm volatile("s_waitcnt vmcnt(0)" ::: "memory"); } \
  BAR(); }

  for (int t = 0; t < NT; t += 2) {
    PHASES(0, 1, t)
    PHASES(1, 0, t + 1)
  }

  // ---- epilogue: bias + optional erf-GELU, guarded rows ----
  const int crow = m0 + wr * 128 + lg * 4;
  const int ccol = n0 + wc * 64 + lrow;
  float bv[4];
#pragma unroll
  for (int ni = 0; ni < 4; ++ni) bv[ni] = be[ccol + ni * 16];
#pragma unroll
  for (int mi = 0; mi < 8; ++mi) {
#pragma unroll
    for (int j = 0; j < 4; ++j) {
      int r = crow + mi * 16 + j;
      if (r < cnt) {
#pragma unroll
        for (int ni = 0; ni < 4; ++ni) {
          float v = acc[mi][ni][j] + bv[ni];
          if (GELU) v = 0.5f * v * (1.f + erff(v * 0.70710678118654752f));
          Out[(size_t)(off + r) * ND + ccol + ni * 16] = __float2half(v);
        }
      }
    }
  }
#undef STAGE_A
#undef STAGE_B
#undef BAR
#undef WLG
#undef P1
#undef P0
#undef MMQ
#undef PHASES
}

// Named per-stage kernels (identical body) so rocprof attributes time per stage.
__global__ __launch_bounds__(512, 1)
void ffn_s1(const __half* __restrict__ A, const __half* __restrict__ Wt,
            const float* __restrict__ Bias, __half* __restrict__ Out,
            const int* __restrict__ counts, const int* __restrict__ offsets,
            const int* __restrict__ idxL) {
  ffn_body<DD, II, true, true, false>(A, Wt, Bias, Out, counts, offsets, idxL);
}
__global__ __launch_bounds__(512, 1)
void ffn_s2(const __half* __restrict__ A, const __half* __restrict__ Wt,
            const float* __restrict__ Bias, __half* __restrict__ Out,
            const int* __restrict__ counts, const int* __restrict__ offsets,
            const int* __restrict__ idxL) {
  // REV: read h1 freshest-first (L3 tail); writes h2 descending so stage-3's
  // ascending read order also hits freshest-first.  (REV proven correct in R7.)
  ffn_body<II, HH, false, true, true>(A, Wt, Bias, Out, counts, offsets, idxL);
}
__global__ __launch_bounds__(512, 1)
void ffn_s3(const __half* __restrict__ A, const __half* __restrict__ Wt,
            const float* __restrict__ Bias, __half* __restrict__ Out,
            const int* __restrict__ counts, const int* __restrict__ offsets,
            const int* __restrict__ idxL) {
  ffn_body<HH, DD, false, false, false>(A, Wt, Bias, Out, counts, offsets, idxL);
}

// ---------------- combine: out[t] = w0*yc[p0] + w1*yc[p1] ----------------
__global__ void combine_kernel(const __half* __restrict__ yc, const float* __restrict__ wTok,
                               const int* __restrict__ posTok, float* __restrict__ out) {
  int t = blockIdx.x;
  int d = threadIdx.x * 4;
  if (d >= DD) return;
  float w0 = wTok[2 * t], w1 = wTok[2 * t + 1];
  const __half2* a = (const __half2*)(yc + (size_t)posTok[2 * t] * DD + d);
  const __half2* b = (const __half2*)(yc + (size_t)posTok[2 * t + 1] * DD + d);
  float2 a0 = __half22float2(a[0]), a1 = __half22float2(a[1]);
  float2 b0 = __half22float2(b[0]), b1 = __half22float2(b[1]);
  float4 r;
  r.x = w0 * a0.x + w1 * b0.x;
  r.y = w0 * a0.y + w1 * b0.y;
  r.z = w0 * a1.x + w1 * b1.x;
  r.w = w0 * a1.y + w1 * b1.y;
  *(float4*)(out + (size_t)t * DD + d) = r;
}

extern "C" void kernel_launch(void* const* d_in, const int* in_sizes, int n_in,
                              void* d_out, int out_size, void* d_ws, size_t ws_size,
                              hipStream_t stream) {
  const float* x  = (const float*)d_in[0];
  const float* Wr = (const float*)d_in[1];
  const float* br = (const float*)d_in[2];
  const float* W1 = (const float*)d_in[3];
  const float* b1 = (const float*)d_in[4];
  const float* W2 = (const float*)d_in[5];
  const float* b2 = (const float*)d_in[6];
  const float* W3 = (const float*)d_in[7];
  const float* b3 = (const float*)d_in[8];
  float* out = (float*)d_out;

  char* ws = (char*)d_ws;
  size_t o = 0;
  auto alloc = [&](size_t bytes) {
    char* p = ws + o;
    o += (bytes + 255) & ~(size_t)255;
    return p;
  };
  __half* xh   = (__half*)alloc((size_t)TK * DD * 2);
  __half* w1t  = (__half*)alloc((size_t)EE * DD * II * 2);
  __half* w2t  = (__half*)alloc((size_t)EE * II * HH * 2);
  __half* w3t  = (__half*)alloc((size_t)EE * HH * DD * 2);
  __half* h1   = (__half*)alloc((size_t)2 * TK * II * 2);
  __half* h2   = (__half*)alloc((size_t)2 * TK * HH * 2);
  __half* yc   = (__half*)alloc((size_t)2 * TK * DD * 2);
  int*   idxL  = (int*)alloc(2 * TK * 4);
  int*   sel   = (int*)alloc(2 * TK * 4);
  float* wTok  = (float*)alloc(2 * TK * 4);
  int*   posT  = (int*)alloc(2 * TK * 4);
  int*   counts  = (int*)alloc(256);
  int*   offsets = (int*)alloc(256);
  int*   cursors = (int*)alloc(256);
  if (o > ws_size) return;  // workspace too small -> loud absmax failure

  hipMemsetAsync(counts, 0, 256, stream);

  cvtT_kernel<<<dim3(II / 64, DD / 64, EE), 256, 0, stream>>>(W1, w1t, DD, II);
  cvtT_kernel<<<dim3(HH / 64, II / 64, EE), 256, 0, stream>>>(W2, w2t, II, HH);
  cvtT_kernel<<<dim3(DD / 64, HH / 64, EE), 256, 0, stream>>>(W3, w3t, HH, DD);
  router_kernel<<<TK / 4, 256, 0, stream>>>(x, Wr, br, counts, sel, wTok, xh);
  offsets_kernel<<<1, 64, 0, stream>>>(counts, offsets, cursors);
  scatter_kernel<<<TK / 256, 256, 0, stream>>>(sel, cursors, idxL, posT);

  ffn_s1<<<dim3(II / 256, 64, EE), 512, 0, stream>>>(xh, w1t, b1, h1, counts, offsets, idxL);
  ffn_s2<<<dim3(HH / 256, 64, EE), 512, 0, stream>>>(h1, w2t, b2, h2, counts, offsets, idxL);
  ffn_s3<<<dim3(DD / 256, 64, EE), 512, 0, stream>>>(h2, w3t, b3, yc, counts, offsets, idxL);

  combine_kernel<<<TK, 192, 0, stream>>>(yc, wTok, posT, out);
}

// Round 12
// 1470.050 us; speedup vs baseline: 1.4899x; 1.0202x over previous
//
#include <hip/hip_runtime.h>
#include <hip/hip_fp16.h>
#include <cstdint>
#include <cstddef>

// Problem constants (setup_inputs: B=8,S=2048,D=768,E=8,I=3072,H=1536,top_k=2)
#define TK 16384   // tokens
#define DD 768
#define EE 8
#define II 3072
#define HH 1536

typedef _Float16 half8 __attribute__((ext_vector_type(8)));
typedef float floatx4 __attribute__((ext_vector_type(4)));

typedef const __attribute__((address_space(1))) uint32_t* gptr_t;
typedef __attribute__((address_space(3))) uint32_t* lptr_t;

#define GLOAD_LDS16(gp, lp) __builtin_amdgcn_global_load_lds( \
    (gptr_t)(const void*)(gp), (lptr_t)(void*)(lp), 16, 0, 0)

// Bijective XCD chunk swizzle (T1/m204). REV flips global order so the
// consumer reads the producer's FRESHEST output first (L3-resident tail).
__device__ __forceinline__ void xcd_swizzle(int& e, int& m, int& n, bool rev) {
  int gx = gridDim.x, gy = gridDim.y;
  int f = (blockIdx.z * gy + blockIdx.y) * gx + blockIdx.x;
  if (rev) f = gx * gy * 8 - 1 - f;
  int xcd = f & 7, idx = f >> 3;
  int chunk = idx / gx, pos = idx - chunk * gx;
  int logical = chunk * (8 * gx) + xcd * gx + pos;
  int mn = gy * gx;
  e = logical / mn;
  int rem = logical - e * mn;
  m = rem / gx;
  n = rem - m * gx;
}

// ------- fp32 [E][K][N] -> fp16 [E][N][K] transpose-convert (64x64 tiles) -------
__global__ __launch_bounds__(256)
void cvtT_kernel(const float* __restrict__ in, __half* __restrict__ out,
                 int K, int N) {
  __shared__ float tile[64][65];
  int e = blockIdx.z;
  const float* inp = in + (size_t)e * K * N + (size_t)(blockIdx.y * 64) * N + blockIdx.x * 64;
  __half* outp = out + (size_t)e * K * N + (size_t)(blockIdx.x * 64) * K + blockIdx.y * 64;
  int s = threadIdx.x;
  int tx = s & 15, r0 = s >> 4;           // tx: float4 col group, r0: row 0..15
#pragma unroll
  for (int i = 0; i < 4; ++i) {
    int k = r0 + i * 16;
    float4 v = *(const float4*)&inp[(size_t)k * N + tx * 4];
    tile[k][tx * 4 + 0] = v.x;
    tile[k][tx * 4 + 1] = v.y;
    tile[k][tx * 4 + 2] = v.z;
    tile[k][tx * 4 + 3] = v.w;
  }
  __syncthreads();
  int kp = s & 31;                         // k-pair 0..31
#pragma unroll
  for (int i = 0; i < 8; ++i) {
    int n = (s >> 5) + i * 8;
    __half2 h = __floats2half2_rn(tile[2 * kp][n], tile[2 * kp + 1][n]);
    *(__half2*)&outp[(size_t)n * K + kp * 2] = h;
  }
}

// ------- router: fp32 logits, top-2, softmax; also emits xh (fp16 copy of x) -------
__global__ __launch_bounds__(256)
void router_kernel(const float* __restrict__ x, const float* __restrict__ Wr,
                   const float* __restrict__ br, int* __restrict__ counts,
                   int* __restrict__ sel, float* __restrict__ wTok,
                   __half* __restrict__ xh) {
  __shared__ float wr_s[EE * DD];  // transposed [e][d], 24KB
  for (int i = threadIdx.x; i < EE * DD; i += 256) {
    int d = i >> 3, e = i & 7;
    wr_s[e * DD + d] = Wr[i];
  }
  __syncthreads();
  int wid = threadIdx.x >> 6, lane = threadIdx.x & 63;
  int t = blockIdx.x * 4 + wid;
  const float* xt = x + (size_t)t * DD;
  float acc[EE];
#pragma unroll
  for (int e = 0; e < EE; ++e) acc[e] = 0.f;
  for (int d = lane; d < DD; d += 64) {
    float xv = xt[d];
#pragma unroll
    for (int e = 0; e < EE; ++e) acc[e] += xv * wr_s[e * DD + d];
  }
#pragma unroll
  for (int off = 32; off > 0; off >>= 1)
#pragma unroll
    for (int e = 0; e < EE; ++e) acc[e] += __shfl_xor(acc[e], off);
  if (lane == 0) {
    float v[EE];
#pragma unroll
    for (int e = 0; e < EE; ++e) v[e] = acc[e] + br[e];
    int i0 = 0;
#pragma unroll
    for (int e = 1; e < EE; ++e) if (v[e] > v[i0]) i0 = e;
    int i1 = (i0 == 0) ? 1 : 0;
#pragma unroll
    for (int e = 0; e < EE; ++e) if (e != i0 && v[e] > v[i1] && e != i1) { if (v[e] > v[i1]) i1 = e; }
    float e1 = __expf(v[i1] - v[i0]);
    float s = 1.f / (1.f + e1);
    sel[2 * t] = i0; sel[2 * t + 1] = i1;
    wTok[2 * t] = s; wTok[2 * t + 1] = e1 * s;
    atomicAdd(&counts[i0], 1);
    atomicAdd(&counts[i1], 1);
  }
  // fused x -> fp16 conversion for this wave's token row
  const float4* xr = (const float4*)xt;
  uint2* xo = (uint2*)(xh + (size_t)t * DD);
#pragma unroll
  for (int j = 0; j < 3; ++j) {
    float4 v = xr[lane + j * 64];
    __half2 a = __floats2half2_rn(v.x, v.y);
    __half2 b = __floats2half2_rn(v.z, v.w);
    uint2 p;
    p.x = *(const unsigned int*)&a;
    p.y = *(const unsigned int*)&b;
    xo[lane + j * 64] = p;
  }
}

// ---------------- offsets (prefix over 8) ----------------
__global__ void offsets_kernel(const int* __restrict__ counts, int* __restrict__ offsets,
                               int* __restrict__ cursors) {
  if (threadIdx.x == 0) {
    int o = 0;
    for (int e = 0; e < EE; ++e) { offsets[e] = o; cursors[e] = o; o += counts[e]; }
  }
}

// ---------------- scatter token->slot ----------------
__global__ void scatter_kernel(const int* __restrict__ sel, int* __restrict__ cursors,
                               int* __restrict__ idxList, int* __restrict__ posTok) {
  int t = blockIdx.x * 256 + threadIdx.x;
  if (t < TK) {
#pragma unroll
    for (int k = 0; k < 2; ++k) {
      int e = sel[2 * t + k];
      int p = atomicAdd(&cursors[e], 1);
      idxList[p] = t;
      posTok[2 * t + k] = p;
    }
  }
}

// ---------------- FFN GEMM body: 256x256 tile, BK=32, deep LDS ring ----------
// 8 waves (2Mx4N). AsF = 5 ring buffers (A staged 4 tiles ahead), BsF = 4
// (B staged 3 ahead); 144KB LDS. Per tile: 12 ds_read_b128 + 4 gloads +
// 32 MFMA + 1 barrier. FIFO ledger (B issued before A each tile):
//   steady in-flight at end-of-tile wait = 14 loads:
//   [A(t+1) B(t+1) A(t+2) B(t+2) A(t+3) B(t+3) A(t+4)] x2 chronological
//   vmcnt(10) retires exactly A(t+1),B(t+1) -> tile t+1 ready; A(t+2..4)
//   stay in flight => A issue->wait distance 3-4 tiles (~1500cy) > HBM ~900cy.
// WAR: stage target A(t+4)%5 / B(t+3)%4 was last READ at tile t-1; those
// reads were consumed by tile t-1's MFMAs before its end barrier.
// Swizzle (BK=32, 64B rows): slot(2b) ^= (row>>1)&3 -> 2-way banks = free.
// Tail (last 4 tiles): vmcnt(0) full drain (conservative, ~4% of tiles).
template<int KD, int ND, bool GATHER, bool GELU, bool REV>
__device__ __forceinline__
void ffn_body(const __half* __restrict__ A, const __half* __restrict__ Wt,
              const float* __restrict__ Bias, __half* __restrict__ Out,
              const int* __restrict__ counts, const int* __restrict__ offsets,
              const int* __restrict__ idxList) {
  constexpr int NT = KD / 32;                // 24 / 96 / 48
  int e, mblk, nblk;
  xcd_swizzle(e, mblk, nblk, REV);
  const int cnt = counts[e];
  const int m0 = mblk * 256;
  if (cnt == 0 || m0 >= cnt) return;
  const int off = offsets[e];
  const int n0 = nblk * 256;
  const __half* We = Wt + (size_t)e * KD * ND;
  const float* be = Bias + (size_t)e * ND;

  __shared__ __align__(16) __half AsF[5 * 256 * 32];   // 80 KB, 16KB/buf
  __shared__ __align__(16) __half BsF[4 * 256 * 32];   // 64 KB

  const int tid = threadIdx.x;
  // staging: load i covers rows i*128 + (tid>>2); col group sc = tid&3;
  // swizzled source col (halfs) = (sc ^ ((row>>1)&3))*8 ; row>>1 bits same
  // for i=0/1 (+128 preserves (row>>1)&3? 128>>1=64, 64&3=0 -> yes).
  const int colh = (((tid & 3) ^ ((tid >> 3) & 3)) << 3);
  const __half* aptr2[2];
  const __half* bptr2[2];
#pragma unroll
  for (int i = 0; i < 2; ++i) {
    int r = i * 128 + (tid >> 2);
    int gr = m0 + r; if (gr > cnt - 1) gr = cnt - 1;   // clamp (writes guarded)
    size_t arow = GATHER ? (size_t)idxList[off + gr] : (size_t)(off + gr);
    aptr2[i] = A + arow * KD + colh;
    bptr2[i] = We + (size_t)(n0 + r) * KD + colh;
  }

#define STA(WOFF, TS) do { \
    GLOAD_LDS16(aptr2[0] + (TS) * 32, (char*)AsF + (WOFF) + tid * 16); \
    GLOAD_LDS16(aptr2[1] + (TS) * 32, (char*)AsF + (WOFF) + tid * 16 + 8192); } while (0)
#define STB(WOFF, TS) do { \
    GLOAD_LDS16(bptr2[0] + (TS) * 32, (char*)BsF + (WOFF) + tid * 16); \
    GLOAD_LDS16(bptr2[1] + (TS) * 32, (char*)BsF + (WOFF) + tid * 16 + 8192); } while (0)

  const int lane = tid & 63, wv = tid >> 6;
  const int wr = wv >> 2, wc = wv & 3;       // 2 x 4 wave grid
  const int lrow = lane & 15, lg = lane >> 4;
  const int slotSwz = lg ^ ((lrow >> 1) & 3);
  const int aBase = (wr * 128 + lrow) * 64 + slotSwz * 16;  // bytes; +mi*1024
  const int bBase = (wc * 64 + lrow) * 64 + slotSwz * 16;   // bytes; +ni*1024

  floatx4 acc[8][4];
#pragma unroll
  for (int mi = 0; mi < 8; ++mi)
#pragma unroll
    for (int ni = 0; ni < 4; ++ni) acc[mi][ni] = (floatx4){0.f, 0.f, 0.f, 0.f};

  // ---- prologue: A(0),B(0),A(1),B(1),A(2),B(2),A(3) = 14 loads ----
  STA(0 * 16384, 0);
  STB(0 * 16384, 0);
  STA(1 * 16384, 1);
  STB(1 * 16384, 1);
  STA(2 * 16384, 2);
  STB(2 * 16384, 2);
  STA(3 * 16384, 3);
  asm volatile("s_waitcnt vmcnt(10)" ::: "memory");  // retires A(0),B(0)
  __builtin_amdgcn_s_barrier();
  __builtin_amdgcn_sched_barrier(0);

  int rA = 0, wA = 4 * 16384;    // byte offsets into AsF ring (tile t / t+4)
  int rB = 0, wB = 3 * 16384;    // byte offsets into BsF ring (tile t / t+3)

#pragma unroll 1
  for (int t = 0; t < NT; ++t) {
    half8 af[8], bf[4];
#pragma unroll
    for (int mi = 0; mi < 8; ++mi)
      af[mi] = *(const half8*)((const char*)AsF + rA + aBase + mi * 1024);
#pragma unroll
    for (int ni = 0; ni < 4; ++ni)
      bf[ni] = *(const half8*)((const char*)BsF + rB + bBase + ni * 1024);
    if (t + 3 < NT) STB(wB, t + 3);
    if (t + 4 < NT) STA(wA, t + 4);
    __builtin_amdgcn_s_setprio(1);
#pragma unroll
    for (int mi = 0; mi < 8; ++mi)
#pragma unroll
      for (int ni = 0; ni < 4; ++ni)
        acc[mi][ni] = __builtin_amdgcn_mfma_f32_16x16x32_f16(
            af[mi], bf[ni], acc[mi][ni], 0, 0, 0);
    __builtin_amdgcn_s_setprio(0);
    if (t + 4 < NT) { asm volatile("s_waitcnt vmcnt(10)" ::: "memory"); }
    else            { asm volatile("s_waitcnt vmcnt(0)"  ::: "memory"); }
    __builtin_amdgcn_s_barrier();
    __builtin_amdgcn_sched_barrier(0);
    rA += 16384; if (rA == 5 * 16384) rA = 0;
    wA += 16384; if (wA == 5 * 16384) wA = 0;
    rB += 16384; if (rB == 4 * 16384) rB = 0;
    wB += 16384; if (wB == 4 * 16384) wB = 0;
  }

  // ---- epilogue: bias + optional erf-GELU, guarded rows ----
  const int crow = m0 + wr * 128 + lg * 4;
  const int ccol = n0 + wc * 64 + lrow;
  float bv[4];
#pragma unroll
  for (int ni = 0; ni < 4; ++ni) bv[ni] = be[ccol + ni * 16];
#pragma unroll
  for (int mi = 0; mi < 8; ++mi) {
#pragma unroll
    for (int j = 0; j < 4; ++j) {
      int r = crow + mi * 16 + j;
      if (r < cnt) {
#pragma unroll
        for (int ni = 0; ni < 4; ++ni) {
          float v = acc[mi][ni][j] + bv[ni];
          if (GELU) v = 0.5f * v * (1.f + erff(v * 0.70710678118654752f));
          Out[(size_t)(off + r) * ND + ccol + ni * 16] = __float2half(v);
        }
      }
    }
  }
#undef STA
#undef STB
}

// Named per-stage kernels (identical body) so rocprof attributes time per stage.
__global__ __launch_bounds__(512, 1)
void ffn_s1(const __half* __restrict__ A, const __half* __restrict__ Wt,
            const float* __restrict__ Bias, __half* __restrict__ Out,
            const int* __restrict__ counts, const int* __restrict__ offsets,
            const int* __restrict__ idxL) {
  ffn_body<DD, II, true, true, false>(A, Wt, Bias, Out, counts, offsets, idxL);
}
__global__ __launch_bounds__(512, 1)
void ffn_s2(const __half* __restrict__ A, const __half* __restrict__ Wt,
            const float* __restrict__ Bias, __half* __restrict__ Out,
            const int* __restrict__ counts, const int* __restrict__ offsets,
            const int* __restrict__ idxL) {
  // REV: read h1 freshest-first (L3 tail); writes h2 descending so stage-3's
  // ascending read order also hits freshest-first.
  ffn_body<II, HH, false, true, true>(A, Wt, Bias, Out, counts, offsets, idxL);
}
__global__ __launch_bounds__(512, 1)
void ffn_s3(const __half* __restrict__ A, const __half* __restrict__ Wt,
            const float* __restrict__ Bias, __half* __restrict__ Out,
            const int* __restrict__ counts, const int* __restrict__ offsets,
            const int* __restrict__ idxL) {
  ffn_body<HH, DD, false, false, false>(A, Wt, Bias, Out, counts, offsets, idxL);
}

// ---------------- combine: out[t] = w0*yc[p0] + w1*yc[p1] ----------------
__global__ void combine_kernel(const __half* __restrict__ yc, const float* __restrict__ wTok,
                               const int* __restrict__ posTok, float* __restrict__ out) {
  int t = blockIdx.x;
  int d = threadIdx.x * 4;
  if (d >= DD) return;
  float w0 = wTok[2 * t], w1 = wTok[2 * t + 1];
  const __half2* a = (const __half2*)(yc + (size_t)posTok[2 * t] * DD + d);
  const __half2* b = (const __half2*)(yc + (size_t)posTok[2 * t + 1] * DD + d);
  float2 a0 = __half22float2(a[0]), a1 = __half22float2(a[1]);
  float2 b0 = __half22float2(b[0]), b1 = __half22float2(b[1]);
  float4 r;
  r.x = w0 * a0.x + w1 * b0.x;
  r.y = w0 * a0.y + w1 * b0.y;
  r.z = w0 * a1.x + w1 * b1.x;
  r.w = w0 * a1.y + w1 * b1.y;
  *(float4*)(out + (size_t)t * DD + d) = r;
}

extern "C" void kernel_launch(void* const* d_in, const int* in_sizes, int n_in,
                              void* d_out, int out_size, void* d_ws, size_t ws_size,
                              hipStream_t stream) {
  const float* x  = (const float*)d_in[0];
  const float* Wr = (const float*)d_in[1];
  const float* br = (const float*)d_in[2];
  const float* W1 = (const float*)d_in[3];
  const float* b1 = (const float*)d_in[4];
  const float* W2 = (const float*)d_in[5];
  const float* b2 = (const float*)d_in[6];
  const float* W3 = (const float*)d_in[7];
  const float* b3 = (const float*)d_in[8];
  float* out = (float*)d_out;

  char* ws = (char*)d_ws;
  size_t o = 0;
  auto alloc = [&](size_t bytes) {
    char* p = ws + o;
    o += (bytes + 255) & ~(size_t)255;
    return p;
  };
  __half* xh   = (__half*)alloc((size_t)TK * DD * 2);
  __half* w1t  = (__half*)alloc((size_t)EE * DD * II * 2);
  __half* w2t  = (__half*)alloc((size_t)EE * II * HH * 2);
  __half* w3t  = (__half*)alloc((size_t)EE * HH * DD * 2);
  __half* h1   = (__half*)alloc((size_t)2 * TK * II * 2);
  __half* h2   = (__half*)alloc((size_t)2 * TK * HH * 2);
  __half* yc   = (__half*)alloc((size_t)2 * TK * DD * 2);
  int*   idxL  = (int*)alloc(2 * TK * 4);
  int*   sel   = (int*)alloc(2 * TK * 4);
  float* wTok  = (float*)alloc(2 * TK * 4);
  int*   posT  = (int*)alloc(2 * TK * 4);
  int*   counts  = (int*)alloc(256);
  int*   offsets = (int*)alloc(256);
  int*   cursors = (int*)alloc(256);
  if (o > ws_size) return;  // workspace too small -> loud absmax failure

  hipMemsetAsync(counts, 0, 256, stream);

  cvtT_kernel<<<dim3(II / 64, DD / 64, EE), 256, 0, stream>>>(W1, w1t, DD, II);
  cvtT_kernel<<<dim3(HH / 64, II / 64, EE), 256, 0, stream>>>(W2, w2t, II, HH);
  cvtT_kernel<<<dim3(DD / 64, HH / 64, EE), 256, 0, stream>>>(W3, w3t, HH, DD);
  router_kernel<<<TK / 4, 256, 0, stream>>>(x, Wr, br, counts, sel, wTok, xh);
  offsets_kernel<<<1, 64, 0, stream>>>(counts, offsets, cursors);
  scatter_kernel<<<TK / 256, 256, 0, stream>>>(sel, cursors, idxL, posT);

  ffn_s1<<<dim3(II / 256, 64, EE), 512, 0, stream>>>(xh, w1t, b1, h1, counts, offsets, idxL);
  ffn_s2<<<dim3(HH / 256, 64, EE), 512, 0, stream>>>(h1, w2t, b2, h2, counts, offsets, idxL);
  ffn_s3<<<dim3(DD / 256, 64, EE), 512, 0, stream>>>(h2, w3t, b3, yc, counts, offsets, idxL);

  combine_kernel<<<TK, 192, 0, stream>>>(yc, wTok, posT, out);
}

// Round 13
// 1441.138 us; speedup vs baseline: 1.5198x; 1.0201x over previous
//
#include <hip/hip_runtime.h>
#include <hip/hip_fp16.h>
#include <cstdint>
#include <cstddef>

// Problem constants (setup_inputs: B=8,S=2048,D=768,E=8,I=3072,H=1536,top_k=2)
#define TK 16384   // tokens
#define DD 768
#define EE 8
#define II 3072
#define HH 1536

typedef _Float16 half8 __attribute__((ext_vector_type(8)));
typedef float floatx4 __attribute__((ext_vector_type(4)));

typedef const __attribute__((address_space(1))) uint32_t* gptr_t;
typedef __attribute__((address_space(3))) uint32_t* lptr_t;

#define GLOAD_LDS16(gp, lp) __builtin_amdgcn_global_load_lds( \
    (gptr_t)(const void*)(gp), (lptr_t)(void*)(lp), 16, 0, 0)

// Bijective XCD chunk swizzle (T1/m204). REV flips global order so the
// consumer reads the producer's FRESHEST output first (L3-resident tail).
__device__ __forceinline__ void xcd_swizzle(int& e, int& m, int& n, bool rev) {
  int gx = gridDim.x, gy = gridDim.y;
  int f = (blockIdx.z * gy + blockIdx.y) * gx + blockIdx.x;
  if (rev) f = gx * gy * 8 - 1 - f;
  int xcd = f & 7, idx = f >> 3;
  int chunk = idx / gx, pos = idx - chunk * gx;
  int logical = chunk * (8 * gx) + xcd * gx + pos;
  int mn = gy * gx;
  e = logical / mn;
  int rem = logical - e * mn;
  m = rem / gx;
  n = rem - m * gx;
}

// ------- fp32 [E][K][N] -> fp16 [E][N][K] transpose-convert (64x64 tiles) -------
__global__ __launch_bounds__(256)
void cvtT_kernel(const float* __restrict__ in, __half* __restrict__ out,
                 int K, int N) {
  __shared__ float tile[64][65];
  int e = blockIdx.z;
  const float* inp = in + (size_t)e * K * N + (size_t)(blockIdx.y * 64) * N + blockIdx.x * 64;
  __half* outp = out + (size_t)e * K * N + (size_t)(blockIdx.x * 64) * K + blockIdx.y * 64;
  int s = threadIdx.x;
  int tx = s & 15, r0 = s >> 4;           // tx: float4 col group, r0: row 0..15
#pragma unroll
  for (int i = 0; i < 4; ++i) {
    int k = r0 + i * 16;
    float4 v = *(const float4*)&inp[(size_t)k * N + tx * 4];
    tile[k][tx * 4 + 0] = v.x;
    tile[k][tx * 4 + 1] = v.y;
    tile[k][tx * 4 + 2] = v.z;
    tile[k][tx * 4 + 3] = v.w;
  }
  __syncthreads();
  int kp = s & 31;                         // k-pair 0..31
#pragma unroll
  for (int i = 0; i < 8; ++i) {
    int n = (s >> 5) + i * 8;
    __half2 h = __floats2half2_rn(tile[2 * kp][n], tile[2 * kp + 1][n]);
    *(__half2*)&outp[(size_t)n * K + kp * 2] = h;
  }
}

// ------- router: fp32 logits, top-2, softmax; also emits xh (fp16 copy of x) -------
__global__ __launch_bounds__(256)
void router_kernel(const float* __restrict__ x, const float* __restrict__ Wr,
                   const float* __restrict__ br, int* __restrict__ counts,
                   int* __restrict__ sel, float* __restrict__ wTok,
                   __half* __restrict__ xh) {
  __shared__ float wr_s[EE * DD];  // transposed [e][d], 24KB
  for (int i = threadIdx.x; i < EE * DD; i += 256) {
    int d = i >> 3, e = i & 7;
    wr_s[e * DD + d] = Wr[i];
  }
  __syncthreads();
  int wid = threadIdx.x >> 6, lane = threadIdx.x & 63;
  int t = blockIdx.x * 4 + wid;
  const float* xt = x + (size_t)t * DD;
  float acc[EE];
#pragma unroll
  for (int e = 0; e < EE; ++e) acc[e] = 0.f;
  for (int d = lane; d < DD; d += 64) {
    float xv = xt[d];
#pragma unroll
    for (int e = 0; e < EE; ++e) acc[e] += xv * wr_s[e * DD + d];
  }
#pragma unroll
  for (int off = 32; off > 0; off >>= 1)
#pragma unroll
    for (int e = 0; e < EE; ++e) acc[e] += __shfl_xor(acc[e], off);
  if (lane == 0) {
    float v[EE];
#pragma unroll
    for (int e = 0; e < EE; ++e) v[e] = acc[e] + br[e];
    int i0 = 0;
#pragma unroll
    for (int e = 1; e < EE; ++e) if (v[e] > v[i0]) i0 = e;
    int i1 = (i0 == 0) ? 1 : 0;
#pragma unroll
    for (int e = 0; e < EE; ++e) if (e != i0 && v[e] > v[i1] && e != i1) { if (v[e] > v[i1]) i1 = e; }
    float e1 = __expf(v[i1] - v[i0]);
    float s = 1.f / (1.f + e1);
    sel[2 * t] = i0; sel[2 * t + 1] = i1;
    wTok[2 * t] = s; wTok[2 * t + 1] = e1 * s;
    atomicAdd(&counts[i0], 1);
    atomicAdd(&counts[i1], 1);
  }
  // fused x -> fp16 conversion for this wave's token row
  const float4* xr = (const float4*)xt;
  uint2* xo = (uint2*)(xh + (size_t)t * DD);
#pragma unroll
  for (int j = 0; j < 3; ++j) {
    float4 v = xr[lane + j * 64];
    __half2 a = __floats2half2_rn(v.x, v.y);
    __half2 b = __floats2half2_rn(v.z, v.w);
    uint2 p;
    p.x = *(const unsigned int*)&a;
    p.y = *(const unsigned int*)&b;
    xo[lane + j * 64] = p;
  }
}

// ---------------- offsets (prefix over 8) ----------------
__global__ void offsets_kernel(const int* __restrict__ counts, int* __restrict__ offsets,
                               int* __restrict__ cursors) {
  if (threadIdx.x == 0) {
    int o = 0;
    for (int e = 0; e < EE; ++e) { offsets[e] = o; cursors[e] = o; o += counts[e]; }
  }
}

// ---------------- scatter token->slot ----------------
__global__ void scatter_kernel(const int* __restrict__ sel, int* __restrict__ cursors,
                               int* __restrict__ idxList, int* __restrict__ posTok) {
  int t = blockIdx.x * 256 + threadIdx.x;
  if (t < TK) {
#pragma unroll
    for (int k = 0; k < 2; ++k) {
      int e = sel[2 * t + k];
      int p = atomicAdd(&cursors[e], 1);
      idxList[p] = t;
      posTok[2 * t + k] = p;
    }
  }
}

// ---------------- FFN GEMM body: 128x128 tile, BK=32, deep LDS ring ----------
// 4 waves (2Mx2N), 256 threads. Ring: As[3] + Bs[3], 8KB each = 48KB LDS ->
// up to 3 blocks/CU co-resident (R12 lesson: 256²/8-wave = 228 regs/wave =
// 2 waves/SIMD, 1 block/CU, no TLP to hide the per-tile serial chain. 128²/
// 4-wave = ~130 regs -> 3 waves/SIMD + independent 4-wave barriers).
// Per tile: 8 ds_read_b128 + 4 gloads + 16 MFMA + 1 barrier.
// FIFO ledger (B before A per tile, 2 instr each, staged 2 tiles ahead):
//   in-flight after issue = B(t+1),A(t+1),B(t+2),A(t+2) = 8 instr;
//   vmcnt(4) retires B(t+1),A(t+1) -> tile t+1 ready; t+2 stays in flight.
//   Distance ~2 tiles (>= ~2400cy wall) > HBM-miss ~900cy.
// WAR: buf (t+2)%3 last read at tile t-1; those ds_reads drained before
// t-1's trailing barrier; stage issue is after it.
// Swizzle: store col slot s at global slot s^((row>>1)&3); read slot
// lg^((lrow>>1)&3). 2-way bank alias = free; R12 measured 0 conflicts.
template<int KD, int ND, bool GATHER, bool GELU, bool REV>
__device__ __forceinline__
void ffn_body(const __half* __restrict__ A, const __half* __restrict__ Wt,
              const float* __restrict__ Bias, __half* __restrict__ Out,
              const int* __restrict__ counts, const int* __restrict__ offsets,
              const int* __restrict__ idxList) {
  constexpr int NT = KD / 32;                // 24 / 96 / 48
  int e, mblk, nblk;
  xcd_swizzle(e, mblk, nblk, REV);
  const int cnt = counts[e];
  const int m0 = mblk * 128;
  if (cnt == 0 || m0 >= cnt) return;
  const int off = offsets[e];
  const int n0 = nblk * 128;
  const __half* We = Wt + (size_t)e * KD * ND;
  const float* be = Bias + (size_t)e * ND;

  __shared__ __align__(16) __half AsF[3 * 128 * 32];   // 24 KB, 8KB/buf
  __shared__ __align__(16) __half BsF[3 * 128 * 32];   // 24 KB

  const int tid = threadIdx.x;
  // staging: instr i covers rows i*64 + (tid>>2); col group sc = tid&3 (16B);
  // swizzled source col (halfs) = (sc ^ ((row>>1)&3))*8.  (i*64)>>1 & 3 == 0,
  // so colh identical for i=0,1.
  const int colh = (((tid & 3) ^ ((tid >> 3) & 3)) << 3);
  const __half* aptr2[2];
  const __half* bptr2[2];
#pragma unroll
  for (int i = 0; i < 2; ++i) {
    int r = i * 64 + (tid >> 2);
    int gr = m0 + r; if (gr > cnt - 1) gr = cnt - 1;   // clamp (writes guarded)
    size_t arow = GATHER ? (size_t)idxList[off + gr] : (size_t)(off + gr);
    aptr2[i] = A + arow * KD + colh;
    bptr2[i] = We + (size_t)(n0 + r) * KD + colh;
  }

#define STA(WOFF, TS) do { \
    GLOAD_LDS16(aptr2[0] + (TS) * 32, (char*)AsF + (WOFF) + tid * 16); \
    GLOAD_LDS16(aptr2[1] + (TS) * 32, (char*)AsF + (WOFF) + tid * 16 + 4096); } while (0)
#define STB(WOFF, TS) do { \
    GLOAD_LDS16(bptr2[0] + (TS) * 32, (char*)BsF + (WOFF) + tid * 16); \
    GLOAD_LDS16(bptr2[1] + (TS) * 32, (char*)BsF + (WOFF) + tid * 16 + 4096); } while (0)

  const int lane = tid & 63, wv = tid >> 6;
  const int wr = wv >> 1, wc = wv & 1;       // 2 x 2 wave grid
  const int lrow = lane & 15, lg = lane >> 4;
  const int slotSwz = lg ^ ((lrow >> 1) & 3);
  const int aBase = (wr * 64 + lrow) * 64 + slotSwz * 16;  // bytes; +mi*1024
  const int bBase = (wc * 64 + lrow) * 64 + slotSwz * 16;  // bytes; +ni*1024

  floatx4 acc[4][4];
#pragma unroll
  for (int mi = 0; mi < 4; ++mi)
#pragma unroll
    for (int ni = 0; ni < 4; ++ni) acc[mi][ni] = (floatx4){0.f, 0.f, 0.f, 0.f};

  // ---- prologue: B(0),A(0),B(1),A(1) = 8 instr ----
  STB(0, 0);
  STA(0, 0);
  STB(8192, 1);
  STA(8192, 1);
  asm volatile("s_waitcnt vmcnt(4)" ::: "memory");  // retires B(0),A(0)
  __builtin_amdgcn_s_barrier();
  __builtin_amdgcn_sched_barrier(0);

  int rBuf = 0, wBuf = 2 * 8192;   // byte offsets into rings (tile t / t+2)

#pragma unroll 1
  for (int t = 0; t < NT; ++t) {
    half8 af[4], bf[4];
#pragma unroll
    for (int mi = 0; mi < 4; ++mi)
      af[mi] = *(const half8*)((const char*)AsF + rBuf + aBase + mi * 1024);
#pragma unroll
    for (int ni = 0; ni < 4; ++ni)
      bf[ni] = *(const half8*)((const char*)BsF + rBuf + bBase + ni * 1024);
    if (t + 2 < NT) { STB(wBuf, t + 2); STA(wBuf, t + 2); }
    __builtin_amdgcn_s_setprio(1);
#pragma unroll
    for (int mi = 0; mi < 4; ++mi)
#pragma unroll
      for (int ni = 0; ni < 4; ++ni)
        acc[mi][ni] = __builtin_amdgcn_mfma_f32_16x16x32_f16(
            af[mi], bf[ni], acc[mi][ni], 0, 0, 0);
    __builtin_amdgcn_s_setprio(0);
    if (t + 2 < NT) { asm volatile("s_waitcnt vmcnt(4)" ::: "memory"); }
    else            { asm volatile("s_waitcnt vmcnt(0)" ::: "memory"); }
    __builtin_amdgcn_s_barrier();
    __builtin_amdgcn_sched_barrier(0);
    rBuf += 8192; if (rBuf == 3 * 8192) rBuf = 0;
    wBuf += 8192; if (wBuf == 3 * 8192) wBuf = 0;
  }

  // ---- epilogue: bias + optional erf-GELU, guarded rows ----
  const int crow = m0 + wr * 64 + lg * 4;
  const int ccol = n0 + wc * 64 + lrow;
  float bv[4];
#pragma unroll
  for (int ni = 0; ni < 4; ++ni) bv[ni] = be[ccol + ni * 16];
#pragma unroll
  for (int mi = 0; mi < 4; ++mi) {
#pragma unroll
    for (int j = 0; j < 4; ++j) {
      int r = crow + mi * 16 + j;
      if (r < cnt) {
#pragma unroll
        for (int ni = 0; ni < 4; ++ni) {
          float v = acc[mi][ni][j] + bv[ni];
          if (GELU) v = 0.5f * v * (1.f + erff(v * 0.70710678118654752f));
          Out[(size_t)(off + r) * ND + ccol + ni * 16] = __float2half(v);
        }
      }
    }
  }
#undef STA
#undef STB
}

// Named per-stage kernels (identical body) so rocprof attributes time per stage.
__global__ __launch_bounds__(256, 2)
void ffn_s1(const __half* __restrict__ A, const __half* __restrict__ Wt,
            const float* __restrict__ Bias, __half* __restrict__ Out,
            const int* __restrict__ counts, const int* __restrict__ offsets,
            const int* __restrict__ idxL) {
  ffn_body<DD, II, true, true, false>(A, Wt, Bias, Out, counts, offsets, idxL);
}
__global__ __launch_bounds__(256, 2)
void ffn_s2(const __half* __restrict__ A, const __half* __restrict__ Wt,
            const float* __restrict__ Bias, __half* __restrict__ Out,
            const int* __restrict__ counts, const int* __restrict__ offsets,
            const int* __restrict__ idxL) {
  // REV: read h1 freshest-first (L3 tail); writes h2 descending so stage-3's
  // ascending read order also hits freshest-first.
  ffn_body<II, HH, false, true, true>(A, Wt, Bias, Out, counts, offsets, idxL);
}
__global__ __launch_bounds__(256, 2)
void ffn_s3(const __half* __restrict__ A, const __half* __restrict__ Wt,
            const float* __restrict__ Bias, __half* __restrict__ Out,
            const int* __restrict__ counts, const int* __restrict__ offsets,
            const int* __restrict__ idxL) {
  ffn_body<HH, DD, false, false, false>(A, Wt, Bias, Out, counts, offsets, idxL);
}

// ---------------- combine: out[t] = w0*yc[p0] + w1*yc[p1] ----------------
__global__ void combine_kernel(const __half* __restrict__ yc, const float* __restrict__ wTok,
                               const int* __restrict__ posTok, float* __restrict__ out) {
  int t = blockIdx.x;
  int d = threadIdx.x * 4;
  if (d >= DD) return;
  float w0 = wTok[2 * t], w1 = wTok[2 * t + 1];
  const __half2* a = (const __half2*)(yc + (size_t)posTok[2 * t] * DD + d);
  const __half2* b = (const __half2*)(yc + (size_t)posTok[2 * t + 1] * DD + d);
  float2 a0 = __half22float2(a[0]), a1 = __half22float2(a[1]);
  float2 b0 = __half22float2(b[0]), b1 = __half22float2(b[1]);
  float4 r;
  r.x = w0 * a0.x + w1 * b0.x;
  r.y = w0 * a0.y + w1 * b0.y;
  r.z = w0 * a1.x + w1 * b1.x;
  r.w = w0 * a1.y + w1 * b1.y;
  *(float4*)(out + (size_t)t * DD + d) = r;
}

extern "C" void kernel_launch(void* const* d_in, const int* in_sizes, int n_in,
                              void* d_out, int out_size, void* d_ws, size_t ws_size,
                              hipStream_t stream) {
  const float* x  = (const float*)d_in[0];
  const float* Wr = (const float*)d_in[1];
  const float* br = (const float*)d_in[2];
  const float* W1 = (const float*)d_in[3];
  const float* b1 = (const float*)d_in[4];
  const float* W2 = (const float*)d_in[5];
  const float* b2 = (const float*)d_in[6];
  const float* W3 = (const float*)d_in[7];
  const float* b3 = (const float*)d_in[8];
  float* out = (float*)d_out;

  char* ws = (char*)d_ws;
  size_t o = 0;
  auto alloc = [&](size_t bytes) {
    char* p = ws + o;
    o += (bytes + 255) & ~(size_t)255;
    return p;
  };
  __half* xh   = (__half*)alloc((size_t)TK * DD * 2);
  __half* w1t  = (__half*)alloc((size_t)EE * DD * II * 2);
  __half* w2t  = (__half*)alloc((size_t)EE * II * HH * 2);
  __half* w3t  = (__half*)alloc((size_t)EE * HH * DD * 2);
  __half* h1   = (__half*)alloc((size_t)2 * TK * II * 2);
  __half* h2   = (__half*)alloc((size_t)2 * TK * HH * 2);
  __half* yc   = (__half*)alloc((size_t)2 * TK * DD * 2);
  int*   idxL  = (int*)alloc(2 * TK * 4);
  int*   sel   = (int*)alloc(2 * TK * 4);
  float* wTok  = (float*)alloc(2 * TK * 4);
  int*   posT  = (int*)alloc(2 * TK * 4);
  int*   counts  = (int*)alloc(256);
  int*   offsets = (int*)alloc(256);
  int*   cursors = (int*)alloc(256);
  if (o > ws_size) return;  // workspace too small -> loud absmax failure

  hipMemsetAsync(counts, 0, 256, stream);

  cvtT_kernel<<<dim3(II / 64, DD / 64, EE), 256, 0, stream>>>(W1, w1t, DD, II);
  cvtT_kernel<<<dim3(HH / 64, II / 64, EE), 256, 0, stream>>>(W2, w2t, II, HH);
  cvtT_kernel<<<dim3(DD / 64, HH / 64, EE), 256, 0, stream>>>(W3, w3t, HH, DD);
  router_kernel<<<TK / 4, 256, 0, stream>>>(x, Wr, br, counts, sel, wTok, xh);
  offsets_kernel<<<1, 64, 0, stream>>>(counts, offsets, cursors);
  scatter_kernel<<<TK / 256, 256, 0, stream>>>(sel, cursors, idxL, posT);

  ffn_s1<<<dim3(II / 128, 128, EE), 256, 0, stream>>>(xh, w1t, b1, h1, counts, offsets, idxL);
  ffn_s2<<<dim3(HH / 128, 128, EE), 256, 0, stream>>>(h1, w2t, b2, h2, counts, offsets, idxL);
  ffn_s3<<<dim3(DD / 128, 128, EE), 256, 0, stream>>>(h2, w3t, b3, yc, counts, offsets, idxL);

  combine_kernel<<<TK, 192, 0, stream>>>(yc, wTok, posT, out);
}

// Round 14
// 1425.250 us; speedup vs baseline: 1.5368x; 1.0111x over previous
//
#include <hip/hip_runtime.h>
#include <hip/hip_fp16.h>
#include <cstdint>
#include <cstddef>

// Problem constants (setup_inputs: B=8,S=2048,D=768,E=8,I=3072,H=1536,top_k=2)
#define TK 16384   // tokens
#define DD 768
#define EE 8
#define II 3072
#define HH 1536

typedef _Float16 half8 __attribute__((ext_vector_type(8)));
typedef float floatx4 __attribute__((ext_vector_type(4)));

typedef const __attribute__((address_space(1))) uint32_t* gptr_t;
typedef __attribute__((address_space(3))) uint32_t* lptr_t;

#define GLOAD_LDS16(gp, lp) __builtin_amdgcn_global_load_lds( \
    (gptr_t)(const void*)(gp), (lptr_t)(void*)(lp), 16, 0, 0)

// Bijective XCD chunk swizzle (T1/m204). REV flips global order so the
// consumer reads the producer's FRESHEST output first (L3-resident tail).
__device__ __forceinline__ void xcd_swizzle(int& e, int& m, int& n, bool rev) {
  int gx = gridDim.x, gy = gridDim.y;
  int f = (blockIdx.z * gy + blockIdx.y) * gx + blockIdx.x;
  if (rev) f = gx * gy * 8 - 1 - f;
  int xcd = f & 7, idx = f >> 3;
  int chunk = idx / gx, pos = idx - chunk * gx;
  int logical = chunk * (8 * gx) + xcd * gx + pos;
  int mn = gy * gx;
  e = logical / mn;
  int rem = logical - e * mn;
  m = rem / gx;
  n = rem - m * gx;
}

// ------- fp32 [E][K][N] -> fp16 [E][N][K] transpose-convert (64x64 tiles) -------
__global__ __launch_bounds__(256)
void cvtT_kernel(const float* __restrict__ in, __half* __restrict__ out,
                 int K, int N) {
  __shared__ float tile[64][65];
  int e = blockIdx.z;
  const float* inp = in + (size_t)e * K * N + (size_t)(blockIdx.y * 64) * N + blockIdx.x * 64;
  __half* outp = out + (size_t)e * K * N + (size_t)(blockIdx.x * 64) * K + blockIdx.y * 64;
  int s = threadIdx.x;
  int tx = s & 15, r0 = s >> 4;           // tx: float4 col group, r0: row 0..15
#pragma unroll
  for (int i = 0; i < 4; ++i) {
    int k = r0 + i * 16;
    float4 v = *(const float4*)&inp[(size_t)k * N + tx * 4];
    tile[k][tx * 4 + 0] = v.x;
    tile[k][tx * 4 + 1] = v.y;
    tile[k][tx * 4 + 2] = v.z;
    tile[k][tx * 4 + 3] = v.w;
  }
  __syncthreads();
  int kp = s & 31;                         // k-pair 0..31
#pragma unroll
  for (int i = 0; i < 8; ++i) {
    int n = (s >> 5) + i * 8;
    __half2 h = __floats2half2_rn(tile[2 * kp][n], tile[2 * kp + 1][n]);
    *(__half2*)&outp[(size_t)n * K + kp * 2] = h;
  }
}

// ------- router: fp32 logits, top-2, softmax; also emits xh (fp16 copy of x) -------
__global__ __launch_bounds__(256)
void router_kernel(const float* __restrict__ x, const float* __restrict__ Wr,
                   const float* __restrict__ br, int* __restrict__ counts,
                   int* __restrict__ sel, float* __restrict__ wTok,
                   __half* __restrict__ xh) {
  __shared__ float wr_s[EE * DD];  // transposed [e][d], 24KB
  for (int i = threadIdx.x; i < EE * DD; i += 256) {
    int d = i >> 3, e = i & 7;
    wr_s[e * DD + d] = Wr[i];
  }
  __syncthreads();
  int wid = threadIdx.x >> 6, lane = threadIdx.x & 63;
  int t = blockIdx.x * 4 + wid;
  const float* xt = x + (size_t)t * DD;
  float acc[EE];
#pragma unroll
  for (int e = 0; e < EE; ++e) acc[e] = 0.f;
  for (int d = lane; d < DD; d += 64) {
    float xv = xt[d];
#pragma unroll
    for (int e = 0; e < EE; ++e) acc[e] += xv * wr_s[e * DD + d];
  }
#pragma unroll
  for (int off = 32; off > 0; off >>= 1)
#pragma unroll
    for (int e = 0; e < EE; ++e) acc[e] += __shfl_xor(acc[e], off);
  if (lane == 0) {
    float v[EE];
#pragma unroll
    for (int e = 0; e < EE; ++e) v[e] = acc[e] + br[e];
    int i0 = 0;
#pragma unroll
    for (int e = 1; e < EE; ++e) if (v[e] > v[i0]) i0 = e;
    int i1 = (i0 == 0) ? 1 : 0;
#pragma unroll
    for (int e = 0; e < EE; ++e) if (e != i0 && v[e] > v[i1] && e != i1) { if (v[e] > v[i1]) i1 = e; }
    float e1 = __expf(v[i1] - v[i0]);
    float s = 1.f / (1.f + e1);
    sel[2 * t] = i0; sel[2 * t + 1] = i1;
    wTok[2 * t] = s; wTok[2 * t + 1] = e1 * s;
    atomicAdd(&counts[i0], 1);
    atomicAdd(&counts[i1], 1);
  }
  // fused x -> fp16 conversion for this wave's token row
  const float4* xr = (const float4*)xt;
  uint2* xo = (uint2*)(xh + (size_t)t * DD);
#pragma unroll
  for (int j = 0; j < 3; ++j) {
    float4 v = xr[lane + j * 64];
    __half2 a = __floats2half2_rn(v.x, v.y);
    __half2 b = __floats2half2_rn(v.z, v.w);
    uint2 p;
    p.x = *(const unsigned int*)&a;
    p.y = *(const unsigned int*)&b;
    xo[lane + j * 64] = p;
  }
}

// ---------------- offsets (prefix over 8) ----------------
__global__ void offsets_kernel(const int* __restrict__ counts, int* __restrict__ offsets,
                               int* __restrict__ cursors) {
  if (threadIdx.x == 0) {
    int o = 0;
    for (int e = 0; e < EE; ++e) { offsets[e] = o; cursors[e] = o; o += counts[e]; }
  }
}

// ---------------- scatter token->slot ----------------
__global__ void scatter_kernel(const int* __restrict__ sel, int* __restrict__ cursors,
                               int* __restrict__ idxList, int* __restrict__ posTok) {
  int t = blockIdx.x * 256 + threadIdx.x;
  if (t < TK) {
#pragma unroll
    for (int k = 0; k < 2; ++k) {
      int e = sel[2 * t + k];
      int p = atomicAdd(&cursors[e], 1);
      idxList[p] = t;
      posTok[2 * t + k] = p;
    }
  }
}

// ======= BIG body (stage 2): 256x256, 8 waves, BK=32, ring A[5]+B[4] =======
// R12-proven (433us on s2). FIFO ledger: steady in-flight 14 loads; vmcnt(10)
// retires A(t+1),B(t+1); A staged 4 tiles ahead (~3600cy >> 900cy HBM miss).
// WAR: buf (t+4)%5 / (t+3)%4 last read at tile t-1, drained pre-barrier.
template<int KD, int ND, bool GATHER, bool GELU, bool REV>
__device__ __forceinline__
void ffn_body_big(const __half* __restrict__ A, const __half* __restrict__ Wt,
                  const float* __restrict__ Bias, __half* __restrict__ Out,
                  const int* __restrict__ counts, const int* __restrict__ offsets,
                  const int* __restrict__ idxList) {
  constexpr int NT = KD / 32;
  int e, mblk, nblk;
  xcd_swizzle(e, mblk, nblk, REV);
  const int cnt = counts[e];
  const int m0 = mblk * 256;
  if (cnt == 0 || m0 >= cnt) return;
  const int off = offsets[e];
  const int n0 = nblk * 256;
  const __half* We = Wt + (size_t)e * KD * ND;
  const float* be = Bias + (size_t)e * ND;

  __shared__ __align__(16) __half AsF[5 * 256 * 32];   // 80 KB
  __shared__ __align__(16) __half BsF[4 * 256 * 32];   // 64 KB

  const int tid = threadIdx.x;
  const int colh = (((tid & 3) ^ ((tid >> 3) & 3)) << 3);
  const __half* aptr2[2];
  const __half* bptr2[2];
#pragma unroll
  for (int i = 0; i < 2; ++i) {
    int r = i * 128 + (tid >> 2);
    int gr = m0 + r; if (gr > cnt - 1) gr = cnt - 1;
    size_t arow = GATHER ? (size_t)idxList[off + gr] : (size_t)(off + gr);
    aptr2[i] = A + arow * KD + colh;
    bptr2[i] = We + (size_t)(n0 + r) * KD + colh;
  }

#define STA(WOFF, TS) do { \
    GLOAD_LDS16(aptr2[0] + (TS) * 32, (char*)AsF + (WOFF) + tid * 16); \
    GLOAD_LDS16(aptr2[1] + (TS) * 32, (char*)AsF + (WOFF) + tid * 16 + 8192); } while (0)
#define STB(WOFF, TS) do { \
    GLOAD_LDS16(bptr2[0] + (TS) * 32, (char*)BsF + (WOFF) + tid * 16); \
    GLOAD_LDS16(bptr2[1] + (TS) * 32, (char*)BsF + (WOFF) + tid * 16 + 8192); } while (0)

  const int lane = tid & 63, wv = tid >> 6;
  const int wr = wv >> 2, wc = wv & 3;       // 2 x 4 wave grid
  const int lrow = lane & 15, lg = lane >> 4;
  const int slotSwz = lg ^ ((lrow >> 1) & 3);
  const int aBase = (wr * 128 + lrow) * 64 + slotSwz * 16;
  const int bBase = (wc * 64 + lrow) * 64 + slotSwz * 16;

  floatx4 acc[8][4];
#pragma unroll
  for (int mi = 0; mi < 8; ++mi)
#pragma unroll
    for (int ni = 0; ni < 4; ++ni) acc[mi][ni] = (floatx4){0.f, 0.f, 0.f, 0.f};

  STA(0 * 16384, 0);
  STB(0 * 16384, 0);
  STA(1 * 16384, 1);
  STB(1 * 16384, 1);
  STA(2 * 16384, 2);
  STB(2 * 16384, 2);
  STA(3 * 16384, 3);
  asm volatile("s_waitcnt vmcnt(10)" ::: "memory");
  __builtin_amdgcn_s_barrier();
  __builtin_amdgcn_sched_barrier(0);

  int rA = 0, wA = 4 * 16384;
  int rB = 0, wB = 3 * 16384;

#pragma unroll 1
  for (int t = 0; t < NT; ++t) {
    half8 af[8], bf[4];
#pragma unroll
    for (int mi = 0; mi < 8; ++mi)
      af[mi] = *(const half8*)((const char*)AsF + rA + aBase + mi * 1024);
#pragma unroll
    for (int ni = 0; ni < 4; ++ni)
      bf[ni] = *(const half8*)((const char*)BsF + rB + bBase + ni * 1024);
    if (t + 3 < NT) STB(wB, t + 3);
    if (t + 4 < NT) STA(wA, t + 4);
    __builtin_amdgcn_s_setprio(1);
#pragma unroll
    for (int mi = 0; mi < 8; ++mi)
#pragma unroll
      for (int ni = 0; ni < 4; ++ni)
        acc[mi][ni] = __builtin_amdgcn_mfma_f32_16x16x32_f16(
            af[mi], bf[ni], acc[mi][ni], 0, 0, 0);
    __builtin_amdgcn_s_setprio(0);
    if (t + 4 < NT) { asm volatile("s_waitcnt vmcnt(10)" ::: "memory"); }
    else            { asm volatile("s_waitcnt vmcnt(0)"  ::: "memory"); }
    __builtin_amdgcn_s_barrier();
    __builtin_amdgcn_sched_barrier(0);
    rA += 16384; if (rA == 5 * 16384) rA = 0;
    wA += 16384; if (wA == 5 * 16384) wA = 0;
    rB += 16384; if (rB == 4 * 16384) rB = 0;
    wB += 16384; if (wB == 4 * 16384) wB = 0;
  }

  const int crow = m0 + wr * 128 + lg * 4;
  const int ccol = n0 + wc * 64 + lrow;
  float bv[4];
#pragma unroll
  for (int ni = 0; ni < 4; ++ni) bv[ni] = be[ccol + ni * 16];
#pragma unroll
  for (int mi = 0; mi < 8; ++mi) {
#pragma unroll
    for (int j = 0; j < 4; ++j) {
      int r = crow + mi * 16 + j;
      if (r < cnt) {
#pragma unroll
        for (int ni = 0; ni < 4; ++ni) {
          float v = acc[mi][ni][j] + bv[ni];
          if (GELU) v = 0.5f * v * (1.f + erff(v * 0.70710678118654752f));
          Out[(size_t)(off + r) * ND + ccol + ni * 16] = __float2half(v);
        }
      }
    }
  }
#undef STA
#undef STB
}

// ======= SMALL body (stages 1,3): 128x128, 4 waves, BK=32, ring 3+3 =======
// R13-proven. vmcnt(4) retires tile t+1's 4 loads; ~3 blocks/CU TLP.
template<int KD, int ND, bool GATHER, bool GELU, bool REV>
__device__ __forceinline__
void ffn_body_small(const __half* __restrict__ A, const __half* __restrict__ Wt,
                    const float* __restrict__ Bias, __half* __restrict__ Out,
                    const int* __restrict__ counts, const int* __restrict__ offsets,
                    const int* __restrict__ idxList) {
  constexpr int NT = KD / 32;
  int e, mblk, nblk;
  xcd_swizzle(e, mblk, nblk, REV);
  const int cnt = counts[e];
  const int m0 = mblk * 128;
  if (cnt == 0 || m0 >= cnt) return;
  const int off = offsets[e];
  const int n0 = nblk * 128;
  const __half* We = Wt + (size_t)e * KD * ND;
  const float* be = Bias + (size_t)e * ND;

  __shared__ __align__(16) __half AsF[3 * 128 * 32];   // 24 KB
  __shared__ __align__(16) __half BsF[3 * 128 * 32];   // 24 KB

  const int tid = threadIdx.x;
  const int colh = (((tid & 3) ^ ((tid >> 3) & 3)) << 3);
  const __half* aptr2[2];
  const __half* bptr2[2];
#pragma unroll
  for (int i = 0; i < 2; ++i) {
    int r = i * 64 + (tid >> 2);
    int gr = m0 + r; if (gr > cnt - 1) gr = cnt - 1;
    size_t arow = GATHER ? (size_t)idxList[off + gr] : (size_t)(off + gr);
    aptr2[i] = A + arow * KD + colh;
    bptr2[i] = We + (size_t)(n0 + r) * KD + colh;
  }

#define STA(WOFF, TS) do { \
    GLOAD_LDS16(aptr2[0] + (TS) * 32, (char*)AsF + (WOFF) + tid * 16); \
    GLOAD_LDS16(aptr2[1] + (TS) * 32, (char*)AsF + (WOFF) + tid * 16 + 4096); } while (0)
#define STB(WOFF, TS) do { \
    GLOAD_LDS16(bptr2[0] + (TS) * 32, (char*)BsF + (WOFF) + tid * 16); \
    GLOAD_LDS16(bptr2[1] + (TS) * 32, (char*)BsF + (WOFF) + tid * 16 + 4096); } while (0)

  const int lane = tid & 63, wv = tid >> 6;
  const int wr = wv >> 1, wc = wv & 1;       // 2 x 2 wave grid
  const int lrow = lane & 15, lg = lane >> 4;
  const int slotSwz = lg ^ ((lrow >> 1) & 3);
  const int aBase = (wr * 64 + lrow) * 64 + slotSwz * 16;
  const int bBase = (wc * 64 + lrow) * 64 + slotSwz * 16;

  floatx4 acc[4][4];
#pragma unroll
  for (int mi = 0; mi < 4; ++mi)
#pragma unroll
    for (int ni = 0; ni < 4; ++ni) acc[mi][ni] = (floatx4){0.f, 0.f, 0.f, 0.f};

  STB(0, 0);
  STA(0, 0);
  STB(8192, 1);
  STA(8192, 1);
  asm volatile("s_waitcnt vmcnt(4)" ::: "memory");
  __builtin_amdgcn_s_barrier();
  __builtin_amdgcn_sched_barrier(0);

  int rBuf = 0, wBuf = 2 * 8192;

#pragma unroll 1
  for (int t = 0; t < NT; ++t) {
    half8 af[4], bf[4];
#pragma unroll
    for (int mi = 0; mi < 4; ++mi)
      af[mi] = *(const half8*)((const char*)AsF + rBuf + aBase + mi * 1024);
#pragma unroll
    for (int ni = 0; ni < 4; ++ni)
      bf[ni] = *(const half8*)((const char*)BsF + rBuf + bBase + ni * 1024);
    if (t + 2 < NT) { STB(wBuf, t + 2); STA(wBuf, t + 2); }
    __builtin_amdgcn_s_setprio(1);
#pragma unroll
    for (int mi = 0; mi < 4; ++mi)
#pragma unroll
      for (int ni = 0; ni < 4; ++ni)
        acc[mi][ni] = __builtin_amdgcn_mfma_f32_16x16x32_f16(
            af[mi], bf[ni], acc[mi][ni], 0, 0, 0);
    __builtin_amdgcn_s_setprio(0);
    if (t + 2 < NT) { asm volatile("s_waitcnt vmcnt(4)" ::: "memory"); }
    else            { asm volatile("s_waitcnt vmcnt(0)" ::: "memory"); }
    __builtin_amdgcn_s_barrier();
    __builtin_amdgcn_sched_barrier(0);
    rBuf += 8192; if (rBuf == 3 * 8192) rBuf = 0;
    wBuf += 8192; if (wBuf == 3 * 8192) wBuf = 0;
  }

  const int crow = m0 + wr * 64 + lg * 4;
  const int ccol = n0 + wc * 64 + lrow;
  float bv[4];
#pragma unroll
  for (int ni = 0; ni < 4; ++ni) bv[ni] = be[ccol + ni * 16];
#pragma unroll
  for (int mi = 0; mi < 4; ++mi) {
#pragma unroll
    for (int j = 0; j < 4; ++j) {
      int r = crow + mi * 16 + j;
      if (r < cnt) {
#pragma unroll
        for (int ni = 0; ni < 4; ++ni) {
          float v = acc[mi][ni][j] + bv[ni];
          if (GELU) v = 0.5f * v * (1.f + erff(v * 0.70710678118654752f));
          Out[(size_t)(off + r) * ND + ccol + ni * 16] = __float2half(v);
        }
      }
    }
  }
#undef STA
#undef STB
}

// Named per-stage kernels (rocprof attribution).
__global__ __launch_bounds__(256, 2)
void ffn_s1(const __half* __restrict__ A, const __half* __restrict__ Wt,
            const float* __restrict__ Bias, __half* __restrict__ Out,
            const int* __restrict__ counts, const int* __restrict__ offsets,
            const int* __restrict__ idxL) {
  ffn_body_small<DD, II, true, true, false>(A, Wt, Bias, Out, counts, offsets, idxL);
}
__global__ __launch_bounds__(512, 1)
void ffn_s2(const __half* __restrict__ A, const __half* __restrict__ Wt,
            const float* __restrict__ Bias, __half* __restrict__ Out,
            const int* __restrict__ counts, const int* __restrict__ offsets,
            const int* __restrict__ idxL) {
  // REV: read h1 freshest-first (L3 tail); writes h2 descending so stage-3's
  // ascending read order also hits freshest-first.
  ffn_body_big<II, HH, false, true, true>(A, Wt, Bias, Out, counts, offsets, idxL);
}
__global__ __launch_bounds__(256, 2)
void ffn_s3(const __half* __restrict__ A, const __half* __restrict__ Wt,
            const float* __restrict__ Bias, __half* __restrict__ Out,
            const int* __restrict__ counts, const int* __restrict__ offsets,
            const int* __restrict__ idxL) {
  ffn_body_small<HH, DD, false, false, false>(A, Wt, Bias, Out, counts, offsets, idxL);
}

// ---------------- combine: out[t] = w0*yc[p0] + w1*yc[p1] ----------------
__global__ void combine_kernel(const __half* __restrict__ yc, const float* __restrict__ wTok,
                               const int* __restrict__ posTok, float* __restrict__ out) {
  int t = blockIdx.x;
  int d = threadIdx.x * 4;
  if (d >= DD) return;
  float w0 = wTok[2 * t], w1 = wTok[2 * t + 1];
  const __half2* a = (const __half2*)(yc + (size_t)posTok[2 * t] * DD + d);
  const __half2* b = (const __half2*)(yc + (size_t)posTok[2 * t + 1] * DD + d);
  float2 a0 = __half22float2(a[0]), a1 = __half22float2(a[1]);
  float2 b0 = __half22float2(b[0]), b1 = __half22float2(b[1]);
  float4 r;
  r.x = w0 * a0.x + w1 * b0.x;
  r.y = w0 * a0.y + w1 * b0.y;
  r.z = w0 * a1.x + w1 * b1.x;
  r.w = w0 * a1.y + w1 * b1.y;
  *(float4*)(out + (size_t)t * DD + d) = r;
}

extern "C" void kernel_launch(void* const* d_in, const int* in_sizes, int n_in,
                              void* d_out, int out_size, void* d_ws, size_t ws_size,
                              hipStream_t stream) {
  const float* x  = (const float*)d_in[0];
  const float* Wr = (const float*)d_in[1];
  const float* br = (const float*)d_in[2];
  const float* W1 = (const float*)d_in[3];
  const float* b1 = (const float*)d_in[4];
  const float* W2 = (const float*)d_in[5];
  const float* b2 = (const float*)d_in[6];
  const float* W3 = (const float*)d_in[7];
  const float* b3 = (const float*)d_in[8];
  float* out = (float*)d_out;

  char* ws = (char*)d_ws;
  size_t o = 0;
  auto alloc = [&](size_t bytes) {
    char* p = ws + o;
    o += (bytes + 255) & ~(size_t)255;
    return p;
  };
  __half* xh   = (__half*)alloc((size_t)TK * DD * 2);
  __half* w1t  = (__half*)alloc((size_t)EE * DD * II * 2);
  __half* w2t  = (__half*)alloc((size_t)EE * II * HH * 2);
  __half* w3t  = (__half*)alloc((size_t)EE * HH * DD * 2);
  __half* h1   = (__half*)alloc((size_t)2 * TK * II * 2);
  __half* h2   = (__half*)alloc((size_t)2 * TK * HH * 2);
  __half* yc   = (__half*)alloc((size_t)2 * TK * DD * 2);
  int*   idxL  = (int*)alloc(2 * TK * 4);
  int*   sel   = (int*)alloc(2 * TK * 4);
  float* wTok  = (float*)alloc(2 * TK * 4);
  int*   posT  = (int*)alloc(2 * TK * 4);
  int*   counts  = (int*)alloc(256);
  int*   offsets = (int*)alloc(256);
  int*   cursors = (int*)alloc(256);
  if (o > ws_size) return;  // workspace too small -> loud absmax failure

  hipMemsetAsync(counts, 0, 256, stream);

  cvtT_kernel<<<dim3(II / 64, DD / 64, EE), 256, 0, stream>>>(W1, w1t, DD, II);
  cvtT_kernel<<<dim3(HH / 64, II / 64, EE), 256, 0, stream>>>(W2, w2t, II, HH);
  cvtT_kernel<<<dim3(DD / 64, HH / 64, EE), 256, 0, stream>>>(W3, w3t, HH, DD);
  router_kernel<<<TK / 4, 256, 0, stream>>>(x, Wr, br, counts, sel, wTok, xh);
  offsets_kernel<<<1, 64, 0, stream>>>(counts, offsets, cursors);
  scatter_kernel<<<TK / 256, 256, 0, stream>>>(sel, cursors, idxL, posT);

  ffn_s1<<<dim3(II / 128, 128, EE), 256, 0, stream>>>(xh, w1t, b1, h1, counts, offsets, idxL);
  ffn_s2<<<dim3(HH / 256, 64, EE), 512, 0, stream>>>(h1, w2t, b2, h2, counts, offsets, idxL);
  ffn_s3<<<dim3(DD / 128, 128, EE), 256, 0, stream>>>(h2, w3t, b3, yc, counts, offsets, idxL);

  combine_kernel<<<TK, 192, 0, stream>>>(yc, wTok, posT, out);
}